// Round 2
// baseline (883.066 us; speedup 1.0000x reference)
//
#include <hip/hip_runtime.h>
#include <float.h>
#include <cstdint>

#define BB 16
#define TT 128
#define RG 9
#define DD 512

// ---------------------------------------------------------------------------
// K1: f2f chamfer similarity.
// sim[tb][i][j] = mean_o max_p dot(q[b,i,o,:], t[b,j,p,:]), masked.
// Block: 256 threads = 16 i-frames x 16 j-frames; thread owns full 9x9 acc.
// LDS: both tiles stored [k][frame*12 + region] (pad 9->12 for aligned float4
// reads; q-side 4 distinct addrs/wave, t-side 2-way -> conflict-free-ish).
// grid (8 jt, 8 it, 32 tb)
// ---------------------------------------------------------------------------
__global__ __launch_bounds__(256) void k_f2f(
    const float* __restrict__ anchors,
    const float* __restrict__ positives,
    const float* __restrict__ negatives,
    const float* __restrict__ amask,
    const float* __restrict__ pmask,
    const float* __restrict__ nmask,
    float* __restrict__ simbuf)
{
    __shared__ alignas(16) float qs[32][192];
    __shared__ alignas(16) float ts[32][192];

    const int tid = threadIdx.x;
    const int jt = blockIdx.x, it = blockIdx.y, tb = blockIdx.z;
    const int b = tb & 15;
    const float* __restrict__ tptr = (tb < BB) ? positives : negatives;
    const float* __restrict__ tmk  = (tb < BB) ? pmask : nmask;
    const int i0 = it * 16, j0 = jt * 16;
    const int fi = tid >> 4, jf = tid & 15;

    float acc[9][9];
#pragma unroll
    for (int o = 0; o < 9; ++o)
#pragma unroll
        for (int p = 0; p < 9; ++p) acc[o][p] = 0.f;

    const float* __restrict__ qbase = anchors + (size_t)(b * TT + i0) * RG * DD;
    const float* __restrict__ tbase = tptr    + (size_t)(b * TT + j0) * RG * DD;

    for (int kc = 0; kc < DD; kc += 32) {
        // stage q tile: 144 rows x 32 k = 1152 float4
        for (int e = tid; e < 1152; e += 256) {
            int row = e >> 3, kq = e & 7;
            int fr = row / 9, o = row - fr * 9;
            float4 v = *reinterpret_cast<const float4*>(
                qbase + (size_t)(fr * RG + o) * DD + kc + kq * 4);
            int col = fr * 12 + o;
            int k4 = kq * 4;
            qs[k4 + 0][col] = v.x; qs[k4 + 1][col] = v.y;
            qs[k4 + 2][col] = v.z; qs[k4 + 3][col] = v.w;
        }
        // stage t tile
        for (int e = tid; e < 1152; e += 256) {
            int row = e >> 3, kq = e & 7;
            int fr = row / 9, p = row - fr * 9;
            float4 v = *reinterpret_cast<const float4*>(
                tbase + (size_t)(fr * RG + p) * DD + kc + kq * 4);
            int col = fr * 12 + p;
            int k4 = kq * 4;
            ts[k4 + 0][col] = v.x; ts[k4 + 1][col] = v.y;
            ts[k4 + 2][col] = v.z; ts[k4 + 3][col] = v.w;
        }
        __syncthreads();

        for (int k = 0; k < 32; ++k) {
            float qv[9], tv[9];
            float4 a0 = *reinterpret_cast<const float4*>(&qs[k][fi * 12]);
            float4 a1 = *reinterpret_cast<const float4*>(&qs[k][fi * 12 + 4]);
            float  a2 = qs[k][fi * 12 + 8];
            qv[0] = a0.x; qv[1] = a0.y; qv[2] = a0.z; qv[3] = a0.w;
            qv[4] = a1.x; qv[5] = a1.y; qv[6] = a1.z; qv[7] = a1.w; qv[8] = a2;
            float4 b0 = *reinterpret_cast<const float4*>(&ts[k][jf * 12]);
            float4 b1 = *reinterpret_cast<const float4*>(&ts[k][jf * 12 + 4]);
            float  b2 = ts[k][jf * 12 + 8];
            tv[0] = b0.x; tv[1] = b0.y; tv[2] = b0.z; tv[3] = b0.w;
            tv[4] = b1.x; tv[5] = b1.y; tv[6] = b1.z; tv[7] = b1.w; tv[8] = b2;
#pragma unroll
            for (int o = 0; o < 9; ++o)
#pragma unroll
                for (int p = 0; p < 9; ++p)
                    acc[o][p] = fmaf(qv[o], tv[p], acc[o][p]);
        }
        __syncthreads();
    }

    float s = 0.f;
#pragma unroll
    for (int o = 0; o < 9; ++o) {
        float m = acc[o][0];
#pragma unroll
        for (int p = 1; p < 9; ++p) m = fmaxf(m, acc[o][p]);
        s += m;
    }
    s *= (1.f / 9.f);
    const int i = i0 + fi, j = j0 + jf;
    const float mk = amask[b * TT + i] * tmk[b * TT + j];
    simbuf[((size_t)tb * TT + i) * TT + j] = (mk > 0.f) ? s : 0.f;
}

// ---------------------------------------------------------------------------
// K2: conv1(1->32, 3x3, pad1) + bias + relu + maxpool2.
// Thread = one pooled (y,x), loops all 32 oc. grid (16 yg, 32 tb)
// ---------------------------------------------------------------------------
__global__ __launch_bounds__(256) void k_conv1pool(
    const float* __restrict__ simbuf, const float* __restrict__ w1,
    const float* __restrict__ b1, float* __restrict__ p1)
{
    __shared__ float wl[288];
    __shared__ float bl[32];
    const int tid = threadIdx.x;
    const int tb = blockIdx.y, yg = blockIdx.x;
    // FIX: 288 > blockDim (256) -> must stride, or oc 28..31 read garbage LDS
    for (int e = tid; e < 288; e += 256) wl[e] = w1[e];
    if (tid < 32)  bl[tid] = b1[tid];
    __syncthreads();

    const int y = yg * 4 + (tid >> 6);
    const int x = tid & 63;
    const float* __restrict__ sp = simbuf + (size_t)tb * TT * TT;

    float iv[4][4];
#pragma unroll
    for (int r = 0; r < 4; ++r) {
        const int gy = 2 * y - 1 + r;
#pragma unroll
        for (int c = 0; c < 4; ++c) {
            const int gx = 2 * x - 1 + c;
            iv[r][c] = (gy >= 0 && gy < TT && gx >= 0 && gx < TT)
                           ? sp[gy * TT + gx] : 0.f;
        }
    }
    for (int oc = 0; oc < 32; ++oc) {
        float a00 = 0.f, a01 = 0.f, a10 = 0.f, a11 = 0.f;
#pragma unroll
        for (int rr = 0; rr < 3; ++rr)
#pragma unroll
            for (int cc = 0; cc < 3; ++cc) {
                const float w = wl[oc * 9 + rr * 3 + cc];
                a00 = fmaf(w, iv[rr][cc],         a00);
                a01 = fmaf(w, iv[rr][cc + 1],     a01);
                a10 = fmaf(w, iv[rr + 1][cc],     a10);
                a11 = fmaf(w, iv[rr + 1][cc + 1], a11);
            }
        float m = fmaxf(fmaxf(a00, a01), fmaxf(a10, a11)) + bl[oc];
        m = fmaxf(m, 0.f);
        p1[(((size_t)tb * 32 + oc) * 64 + y) * 64 + x] = m;
    }
}

// ---------------------------------------------------------------------------
// K3: conv2(32->64, 3x3, pad1) + bias + relu + maxpool2.
// Block: (tb, y, xg). Thread = (oc, xs): one pooled out, 4 conv accs.
// ic chunked by 8; weights LDS-staged with pad-73 stride (conflict-free).
// grid (8 xg, 32 y, 32 tb)
// ---------------------------------------------------------------------------
__global__ __launch_bounds__(256) void k_conv2pool(
    const float* __restrict__ p1, const float* __restrict__ w2,
    const float* __restrict__ b2, float* __restrict__ p2)
{
    __shared__ float wl[64 * 73];
    __shared__ float intile[8 * 40];
    const int tid = threadIdx.x;
    const int xg = blockIdx.x, y = blockIdx.y, tb = blockIdx.z;
    const int oc = tid & 63, xs = tid >> 6;
    const int x = xg * 4 + xs;

    float acc4[4] = {0.f, 0.f, 0.f, 0.f};

    for (int icc = 0; icc < 4; ++icc) {
        for (int e = tid; e < 4608; e += 256) {
            const int oc_ = e / 72, rem = e - oc_ * 72;
            wl[oc_ * 73 + rem] = w2[oc_ * 288 + icc * 72 + rem];
        }
        for (int e = tid; e < 320; e += 256) {
            const int ic_ = e / 40, rem = e - ic_ * 40;
            const int r = rem / 10, c = rem - r * 10;
            const int gy = 2 * y - 1 + r, gx = xg * 8 - 1 + c;
            float v = 0.f;
            if (gy >= 0 && gy < 64 && gx >= 0 && gx < 64)
                v = p1[(((size_t)tb * 32 + icc * 8 + ic_) * 64 + gy) * 64 + gx];
            intile[e] = v;
        }
        __syncthreads();
#pragma unroll
        for (int ic = 0; ic < 8; ++ic) {
            float iv[16];
#pragma unroll
            for (int r = 0; r < 4; ++r)
#pragma unroll
                for (int c = 0; c < 4; ++c)
                    iv[r * 4 + c] = intile[ic * 40 + r * 10 + 2 * xs + c];
            float w9[9];
#pragma unroll
            for (int t9 = 0; t9 < 9; ++t9)
                w9[t9] = wl[oc * 73 + ic * 9 + t9];
#pragma unroll
            for (int rr = 0; rr < 3; ++rr)
#pragma unroll
                for (int cc = 0; cc < 3; ++cc) {
                    const float w = w9[rr * 3 + cc];
                    acc4[0] = fmaf(w, iv[rr * 4 + cc],           acc4[0]);
                    acc4[1] = fmaf(w, iv[rr * 4 + cc + 1],       acc4[1]);
                    acc4[2] = fmaf(w, iv[(rr + 1) * 4 + cc],     acc4[2]);
                    acc4[3] = fmaf(w, iv[(rr + 1) * 4 + cc + 1], acc4[3]);
                }
        }
        __syncthreads();
    }
    float m = fmaxf(fmaxf(acc4[0], acc4[1]), fmaxf(acc4[2], acc4[3])) + b2[oc];
    m = fmaxf(m, 0.f);
    p2[(((size_t)tb * 64 + oc) * 32 + y) * 32 + x] = m;
}

// ---------------------------------------------------------------------------
// K4: conv3(64->128, 3x3, pad1) + bias + relu. Output layout [tb][y][x][oc]
// (channel-last so K5's 1x1 reduction reads contiguously).
// Block: (tb, y, xg). Thread = (oc, xh), owns 8 x positions.
// grid (2 xg, 32 y, 32 tb)
// ---------------------------------------------------------------------------
__global__ __launch_bounds__(256) void k_conv3(
    const float* __restrict__ p2, const float* __restrict__ w3,
    const float* __restrict__ b3, float* __restrict__ c3t)
{
    __shared__ float wl[128 * 73];
    __shared__ float intile[8 * 54];
    const int tid = threadIdx.x;
    const int xg = blockIdx.x, y = blockIdx.y, tb = blockIdx.z;
    const int oc = tid & 127, xh = tid >> 7;
    const int x0 = xg * 16 + xh * 8;

    float acc[8];
#pragma unroll
    for (int i = 0; i < 8; ++i) acc[i] = 0.f;

    for (int icc = 0; icc < 8; ++icc) {
        for (int e = tid; e < 9216; e += 256) {
            const int oc_ = e / 72, rem = e - oc_ * 72;
            wl[oc_ * 73 + rem] = w3[oc_ * 576 + icc * 72 + rem];
        }
        for (int e = tid; e < 432; e += 256) {
            const int ic_ = e / 54, rem = e - ic_ * 54;
            const int r = rem / 18, c = rem - r * 18;
            const int gy = y - 1 + r, gx = xg * 16 - 1 + c;
            float v = 0.f;
            if (gy >= 0 && gy < 32 && gx >= 0 && gx < 32)
                v = p2[(((size_t)tb * 64 + icc * 8 + ic_) * 32 + gy) * 32 + gx];
            intile[e] = v;
        }
        __syncthreads();
#pragma unroll
        for (int ic = 0; ic < 8; ++ic) {
            float w9[9];
#pragma unroll
            for (int t9 = 0; t9 < 9; ++t9)
                w9[t9] = wl[oc * 73 + ic * 9 + t9];
            float irow[3][10];
#pragma unroll
            for (int r = 0; r < 3; ++r)
#pragma unroll
                for (int c = 0; c < 10; ++c)
                    irow[r][c] = intile[ic * 54 + r * 18 + xh * 8 + c];
#pragma unroll
            for (int xi = 0; xi < 8; ++xi)
#pragma unroll
                for (int rr = 0; rr < 3; ++rr)
#pragma unroll
                    for (int cc = 0; cc < 3; ++cc)
                        acc[xi] = fmaf(w9[rr * 3 + cc], irow[rr][xi + cc], acc[xi]);
        }
        __syncthreads();
    }
    const float bias = b3[oc];
#pragma unroll
    for (int xi = 0; xi < 8; ++xi) {
        const float v = fmaxf(acc[xi] + bias, 0.f);
        c3t[(((size_t)tb * 32 + y) * 32 + (x0 + xi)) * 128 + oc] = v;
    }
}

// ---------------------------------------------------------------------------
// K5: fconv (1x1, 128->1) + bias, hinge-loss partials, clip, mask pooling,
// v2v row-max/mean -> out[tb]. One block per tb.
// ---------------------------------------------------------------------------
__global__ __launch_bounds__(256) void k_final(
    const float* __restrict__ c3t, const float* __restrict__ fw,
    const float* __restrict__ fb, const float* __restrict__ amask,
    const float* __restrict__ pmask, const float* __restrict__ nmask,
    float* __restrict__ out, float* __restrict__ lossp)
{
    __shared__ alignas(16) float fwl[128];
    __shared__ float qmax4[32], tmax4[32];
    __shared__ float sval[1024];
    __shared__ float red[256];
    __shared__ float rowv[32], rowm[32];
    const int tid = threadIdx.x, tb = blockIdx.x;
    const int b = tb & 15;
    const float* __restrict__ tmk = (tb < BB) ? pmask : nmask;

    if (tid < 128) fwl[tid] = fw[tid];
    if (tid < 32) {
        const float* qp = amask + b * TT + 4 * tid;
        qmax4[tid] = fmaxf(fmaxf(qp[0], qp[1]), fmaxf(qp[2], qp[3]));
        const float* tp = tmk + b * TT + 4 * tid;
        tmax4[tid] = fmaxf(fmaxf(tp[0], tp[1]), fmaxf(tp[2], tp[3]));
    }
    __syncthreads();

    const float fbv = fb[0];
    float lt = 0.f;
    for (int l = 0; l < 4; ++l) {
        const int loc = tid + 256 * l;
        const int y = loc >> 5, x = loc & 31;
        const float* __restrict__ pc = c3t + ((size_t)(tb * 32 + y) * 32 + x) * 128;
        float s = fbv;
        for (int c4 = 0; c4 < 128; c4 += 4) {
            const float4 wv = *reinterpret_cast<const float4*>(&fwl[c4]);
            const float4 cv = *reinterpret_cast<const float4*>(&pc[c4]);
            s += wv.x * cv.x + wv.y * cv.y + wv.z * cv.z + wv.w * cv.w;
        }
        lt += fmaxf(0.f, -1.f - s) + fmaxf(0.f, s - 1.f);
        const float sc = fminf(fmaxf(s, -1.f), 1.f);
        const float m = qmax4[y] * tmax4[x];
        sval[loc] = (m > 0.f) ? sc : -FLT_MAX;
    }
    red[tid] = lt;
    __syncthreads();
    for (int off = 128; off > 0; off >>= 1) {
        if (tid < off) red[tid] += red[tid + off];
        __syncthreads();
    }
    if (tid == 0) lossp[tb] = red[0];

    if (tid < 32) {
        const int y = tid;
        float rm = -FLT_MAX, mm = -FLT_MAX;
        for (int x = 0; x < 32; ++x) {
            const float m = qmax4[y] * tmax4[x];
            mm = fmaxf(mm, m);
            if (m > 0.f) rm = fmaxf(rm, sval[y * 32 + x]);
        }
        rowv[y] = (mm > 0.f) ? rm : 0.f;
        rowm[y] = mm;
    }
    __syncthreads();
    if (tid == 0) {
        float num = 0.f, den = 0.f;
        for (int yy = 0; yy < 32; ++yy) { num += rowv[yy]; den += rowm[yy]; }
        out[tb] = num / den;
    }
}

__global__ void k_losssum(const float* __restrict__ lossp, float* __restrict__ out)
{
    if (threadIdx.x == 0) {
        float s = 0.f;
        for (int i = 0; i < 32; ++i) s += lossp[i];
        out[32] = s;
    }
}

// ---------------------------------------------------------------------------
extern "C" void kernel_launch(void* const* d_in, const int* in_sizes, int n_in,
                              void* d_out, int out_size, void* d_ws, size_t ws_size,
                              hipStream_t stream)
{
    (void)in_sizes; (void)n_in; (void)out_size; (void)ws_size;
    const float* anchors   = (const float*)d_in[0];
    const float* positives = (const float*)d_in[1];
    const float* negatives = (const float*)d_in[2];
    const float* amask     = (const float*)d_in[3];
    const float* pmask     = (const float*)d_in[4];
    const float* nmask     = (const float*)d_in[5];
    const float* w1 = (const float*)d_in[6];
    const float* b1 = (const float*)d_in[7];
    const float* w2 = (const float*)d_in[8];
    const float* b2 = (const float*)d_in[9];
    const float* w3 = (const float*)d_in[10];
    const float* b3 = (const float*)d_in[11];
    const float* fw = (const float*)d_in[12];
    const float* fbias = (const float*)d_in[13];

    float* ws     = (float*)d_ws;
    float* simbuf = ws;                  // 32*128*128      =  524288
    float* p1     = ws + 524288;         // 32*32*64*64     = 4194304
    float* p2     = ws + 4718592;        // 32*64*32*32     = 2097152
    float* c3t    = ws + 6815744;        // 32*32*32*128    = 4194304
    float* lossp  = ws + 11010048;       // 32
    float* outp   = (float*)d_out;       // [0..15] pos, [16..31] neg, [32] loss

    hipLaunchKernelGGL(k_f2f, dim3(8, 8, 32), dim3(256), 0, stream,
                       anchors, positives, negatives, amask, pmask, nmask, simbuf);
    hipLaunchKernelGGL(k_conv1pool, dim3(16, 32), dim3(256), 0, stream,
                       simbuf, w1, b1, p1);
    hipLaunchKernelGGL(k_conv2pool, dim3(8, 32, 32), dim3(256), 0, stream,
                       p1, w2, b2, p2);
    hipLaunchKernelGGL(k_conv3, dim3(2, 32, 32), dim3(256), 0, stream,
                       p2, w3, b3, c3t);
    hipLaunchKernelGGL(k_final, dim3(32), dim3(256), 0, stream,
                       c3t, fw, fbias, amask, pmask, nmask, outp, lossp);
    hipLaunchKernelGGL(k_losssum, dim3(1), dim3(64), 0, stream, lossp, outp);
}

// Round 3
// 463.768 us; speedup vs baseline: 1.9041x; 1.9041x over previous
//
#include <hip/hip_runtime.h>
#include <float.h>
#include <cstdint>

#define BB 16
#define TT 128
#define RG 9
#define DD 512

typedef _Float16 half8 __attribute__((ext_vector_type(8)));
typedef float f32x4 __attribute__((ext_vector_type(4)));

// ---------------------------------------------------------------------------
// K1 (MFMA): f2f chamfer similarity via 16x16x32 f16 MFMA.
// Row order is region-major (row = o*16 + i_local) so each 16x16 MFMA tile is
// one (o,p) pair over a 16x16 frame block -> max_p / mean_o are per-lane.
// Block: 192 thr = 3 waves, o-split {3,3,3}; per wave acc[3][9] f32x4.
// LDS tiles [144 rows][64 k] f16, XOR-swizzled (byte ^= (row&7)<<4).
// grid (8 jt, 8 it, 32 tb), block 192.
// ---------------------------------------------------------------------------
__device__ __forceinline__ half8 ldfrag(const char* base, int row, int ks, int hi)
{
    const int x = ((ks << 6) + (hi << 4)) ^ ((row & 7) << 4);
    return *reinterpret_cast<const half8*>(base + row * 128 + x);
}

__device__ __forceinline__ void stage_tile(char* dst, const float* __restrict__ src,
                                           int kc, int tid)
{
    // 144 rows x 64 k; unit = (row, 8-k group); 1152 units / 192 thr = 6 each
    for (int e = tid; e < 1152; e += 192) {
        const int row = e >> 3, kg = e & 7;
        const int o = row >> 4, il = row & 15;
        const float* g = src + ((size_t)il * RG + o) * DD + kc + kg * 8;
        const float4 v0 = *reinterpret_cast<const float4*>(g);
        const float4 v1 = *reinterpret_cast<const float4*>(g + 4);
        union { _Float16 h[8]; float4 f4; } u;
        u.h[0] = (_Float16)v0.x; u.h[1] = (_Float16)v0.y;
        u.h[2] = (_Float16)v0.z; u.h[3] = (_Float16)v0.w;
        u.h[4] = (_Float16)v1.x; u.h[5] = (_Float16)v1.y;
        u.h[6] = (_Float16)v1.z; u.h[7] = (_Float16)v1.w;
        const int x = (kg << 4) ^ ((row & 7) << 4);
        *reinterpret_cast<float4*>(dst + row * 128 + x) = u.f4;
    }
}

__global__ __launch_bounds__(192) void k_f2f_mfma(
    const float* __restrict__ anchors,
    const float* __restrict__ positives,
    const float* __restrict__ negatives,
    const float* __restrict__ amask,
    const float* __restrict__ pmask,
    const float* __restrict__ nmask,
    float* __restrict__ simbuf)
{
    __shared__ __align__(16) char qs[18432];
    __shared__ __align__(16) char ts[18432];

    const int tid = threadIdx.x;
    const int lane = tid & 63, wave = tid >> 6;
    const int lo = lane & 15, hi = lane >> 4;
    const int jt = blockIdx.x, it = blockIdx.y, tb = blockIdx.z;
    const int b = tb & 15;
    const float* __restrict__ tptr = (tb < BB) ? positives : negatives;
    const float* __restrict__ tmk  = (tb < BB) ? pmask : nmask;
    const int i0 = it * 16, j0 = jt * 16;
    const float* __restrict__ qsrc = anchors + ((size_t)(b * TT + i0)) * RG * DD;
    const float* __restrict__ tsrc = tptr    + ((size_t)(b * TT + j0)) * RG * DD;

    f32x4 acc[3][9];
#pragma unroll
    for (int oi = 0; oi < 3; ++oi)
#pragma unroll
        for (int p = 0; p < 9; ++p)
            acc[oi][p] = (f32x4){0.f, 0.f, 0.f, 0.f};

    const int o0 = wave * 3;

    for (int kc = 0; kc < DD; kc += 64) {
        stage_tile(qs, qsrc, kc, tid);
        stage_tile(ts, tsrc, kc, tid);
        __syncthreads();
#pragma unroll
        for (int ks = 0; ks < 2; ++ks) {
            const half8 a0 = ldfrag(qs, (o0 + 0) * 16 + lo, ks, hi);
            const half8 a1 = ldfrag(qs, (o0 + 1) * 16 + lo, ks, hi);
            const half8 a2 = ldfrag(qs, (o0 + 2) * 16 + lo, ks, hi);
#pragma unroll
            for (int p = 0; p < 9; ++p) {
                const half8 bf = ldfrag(ts, p * 16 + lo, ks, hi);
                acc[0][p] = __builtin_amdgcn_mfma_f32_16x16x32_f16(a0, bf, acc[0][p], 0, 0, 0);
                acc[1][p] = __builtin_amdgcn_mfma_f32_16x16x32_f16(a1, bf, acc[1][p], 0, 0, 0);
                acc[2][p] = __builtin_amdgcn_mfma_f32_16x16x32_f16(a2, bf, acc[2][p], 0, 0, 0);
            }
        }
        __syncthreads();
    }

    // per-lane: sum over my 3 o of (max over 9 p)
    f32x4 part = {0.f, 0.f, 0.f, 0.f};
#pragma unroll
    for (int oi = 0; oi < 3; ++oi) {
        f32x4 m = acc[oi][0];
#pragma unroll
        for (int p = 1; p < 9; ++p) {
            m[0] = fmaxf(m[0], acc[oi][p][0]);
            m[1] = fmaxf(m[1], acc[oi][p][1]);
            m[2] = fmaxf(m[2], acc[oi][p][2]);
            m[3] = fmaxf(m[3], acc[oi][p][3]);
        }
        part[0] += m[0]; part[1] += m[1]; part[2] += m[2]; part[3] += m[3];
    }

    // cross-wave sum (3 waves) via LDS (alias qs; all LDS reads done)
    float* red = reinterpret_cast<float*>(qs);
    *reinterpret_cast<f32x4*>(red + (size_t)(wave * 64 + lane) * 4) = part;
    __syncthreads();
    if (wave == 0) {
        const f32x4 t0 = *reinterpret_cast<const f32x4*>(red + (size_t)lane * 4);
        const f32x4 t1 = *reinterpret_cast<const f32x4*>(red + (size_t)(64 + lane) * 4);
        const f32x4 t2 = *reinterpret_cast<const f32x4*>(red + (size_t)(128 + lane) * 4);
        const int j = j0 + lo;
        const float tm = tmk[b * TT + j];
#pragma unroll
        for (int r = 0; r < 4; ++r) {
            const int i = i0 + hi * 4 + r;
            const float mk = amask[b * TT + i] * tm;
            const float s = (t0[r] + t1[r] + t2[r]) * (1.f / 9.f);
            simbuf[((size_t)tb * TT + i) * TT + j] = (mk > 0.f) ? s : 0.f;
        }
    }
}

// ---------------------------------------------------------------------------
// K2: conv1(1->32, 3x3, pad1) + bias + relu + maxpool2.
// ---------------------------------------------------------------------------
__global__ __launch_bounds__(256) void k_conv1pool(
    const float* __restrict__ simbuf, const float* __restrict__ w1,
    const float* __restrict__ b1, float* __restrict__ p1)
{
    __shared__ float wl[288];
    __shared__ float bl[32];
    const int tid = threadIdx.x;
    const int tb = blockIdx.y, yg = blockIdx.x;
    for (int e = tid; e < 288; e += 256) wl[e] = w1[e];
    if (tid < 32)  bl[tid] = b1[tid];
    __syncthreads();

    const int y = yg * 4 + (tid >> 6);
    const int x = tid & 63;
    const float* __restrict__ sp = simbuf + (size_t)tb * TT * TT;

    float iv[4][4];
#pragma unroll
    for (int r = 0; r < 4; ++r) {
        const int gy = 2 * y - 1 + r;
#pragma unroll
        for (int c = 0; c < 4; ++c) {
            const int gx = 2 * x - 1 + c;
            iv[r][c] = (gy >= 0 && gy < TT && gx >= 0 && gx < TT)
                           ? sp[gy * TT + gx] : 0.f;
        }
    }
    for (int oc = 0; oc < 32; ++oc) {
        float a00 = 0.f, a01 = 0.f, a10 = 0.f, a11 = 0.f;
#pragma unroll
        for (int rr = 0; rr < 3; ++rr)
#pragma unroll
            for (int cc = 0; cc < 3; ++cc) {
                const float w = wl[oc * 9 + rr * 3 + cc];
                a00 = fmaf(w, iv[rr][cc],         a00);
                a01 = fmaf(w, iv[rr][cc + 1],     a01);
                a10 = fmaf(w, iv[rr + 1][cc],     a10);
                a11 = fmaf(w, iv[rr + 1][cc + 1], a11);
            }
        float m = fmaxf(fmaxf(a00, a01), fmaxf(a10, a11)) + bl[oc];
        m = fmaxf(m, 0.f);
        p1[(((size_t)tb * 32 + oc) * 64 + y) * 64 + x] = m;
    }
}

// ---------------------------------------------------------------------------
// K3: conv2(32->64, 3x3, pad1) + bias + relu + maxpool2.
// ---------------------------------------------------------------------------
__global__ __launch_bounds__(256) void k_conv2pool(
    const float* __restrict__ p1, const float* __restrict__ w2,
    const float* __restrict__ b2, float* __restrict__ p2)
{
    __shared__ float wl[64 * 73];
    __shared__ float intile[8 * 40];
    const int tid = threadIdx.x;
    const int xg = blockIdx.x, y = blockIdx.y, tb = blockIdx.z;
    const int oc = tid & 63, xs = tid >> 6;
    const int x = xg * 4 + xs;

    float acc4[4] = {0.f, 0.f, 0.f, 0.f};

    for (int icc = 0; icc < 4; ++icc) {
        for (int e = tid; e < 4608; e += 256) {
            const int oc_ = e / 72, rem = e - oc_ * 72;
            wl[oc_ * 73 + rem] = w2[oc_ * 288 + icc * 72 + rem];
        }
        for (int e = tid; e < 320; e += 256) {
            const int ic_ = e / 40, rem = e - ic_ * 40;
            const int r = rem / 10, c = rem - r * 10;
            const int gy = 2 * y - 1 + r, gx = xg * 8 - 1 + c;
            float v = 0.f;
            if (gy >= 0 && gy < 64 && gx >= 0 && gx < 64)
                v = p1[(((size_t)tb * 32 + icc * 8 + ic_) * 64 + gy) * 64 + gx];
            intile[e] = v;
        }
        __syncthreads();
#pragma unroll
        for (int ic = 0; ic < 8; ++ic) {
            float iv[16];
#pragma unroll
            for (int r = 0; r < 4; ++r)
#pragma unroll
                for (int c = 0; c < 4; ++c)
                    iv[r * 4 + c] = intile[ic * 40 + r * 10 + 2 * xs + c];
            float w9[9];
#pragma unroll
            for (int t9 = 0; t9 < 9; ++t9)
                w9[t9] = wl[oc * 73 + ic * 9 + t9];
#pragma unroll
            for (int rr = 0; rr < 3; ++rr)
#pragma unroll
                for (int cc = 0; cc < 3; ++cc) {
                    const float w = w9[rr * 3 + cc];
                    acc4[0] = fmaf(w, iv[rr * 4 + cc],           acc4[0]);
                    acc4[1] = fmaf(w, iv[rr * 4 + cc + 1],       acc4[1]);
                    acc4[2] = fmaf(w, iv[(rr + 1) * 4 + cc],     acc4[2]);
                    acc4[3] = fmaf(w, iv[(rr + 1) * 4 + cc + 1], acc4[3]);
                }
        }
        __syncthreads();
    }
    float m = fmaxf(fmaxf(acc4[0], acc4[1]), fmaxf(acc4[2], acc4[3])) + b2[oc];
    m = fmaxf(m, 0.f);
    p2[(((size_t)tb * 64 + oc) * 32 + y) * 32 + x] = m;
}

// ---------------------------------------------------------------------------
// K4: conv3(64->128, 3x3, pad1) + bias + relu. Output [tb][y][x][oc].
// ---------------------------------------------------------------------------
__global__ __launch_bounds__(256) void k_conv3(
    const float* __restrict__ p2, const float* __restrict__ w3,
    const float* __restrict__ b3, float* __restrict__ c3t)
{
    __shared__ float wl[128 * 73];
    __shared__ float intile[8 * 54];
    const int tid = threadIdx.x;
    const int xg = blockIdx.x, y = blockIdx.y, tb = blockIdx.z;
    const int oc = tid & 127, xh = tid >> 7;
    const int x0 = xg * 16 + xh * 8;

    float acc[8];
#pragma unroll
    for (int i = 0; i < 8; ++i) acc[i] = 0.f;

    for (int icc = 0; icc < 8; ++icc) {
        for (int e = tid; e < 9216; e += 256) {
            const int oc_ = e / 72, rem = e - oc_ * 72;
            wl[oc_ * 73 + rem] = w3[oc_ * 576 + icc * 72 + rem];
        }
        for (int e = tid; e < 432; e += 256) {
            const int ic_ = e / 54, rem = e - ic_ * 54;
            const int r = rem / 18, c = rem - r * 18;
            const int gy = y - 1 + r, gx = xg * 16 - 1 + c;
            float v = 0.f;
            if (gy >= 0 && gy < 32 && gx >= 0 && gx < 32)
                v = p2[(((size_t)tb * 64 + icc * 8 + ic_) * 32 + gy) * 32 + gx];
            intile[e] = v;
        }
        __syncthreads();
#pragma unroll
        for (int ic = 0; ic < 8; ++ic) {
            float w9[9];
#pragma unroll
            for (int t9 = 0; t9 < 9; ++t9)
                w9[t9] = wl[oc * 73 + ic * 9 + t9];
            float irow[3][10];
#pragma unroll
            for (int r = 0; r < 3; ++r)
#pragma unroll
                for (int c = 0; c < 10; ++c)
                    irow[r][c] = intile[ic * 54 + r * 18 + xh * 8 + c];
#pragma unroll
            for (int xi = 0; xi < 8; ++xi)
#pragma unroll
                for (int rr = 0; rr < 3; ++rr)
#pragma unroll
                    for (int cc = 0; cc < 3; ++cc)
                        acc[xi] = fmaf(w9[rr * 3 + cc], irow[rr][xi + cc], acc[xi]);
        }
        __syncthreads();
    }
    const float bias = b3[oc];
#pragma unroll
    for (int xi = 0; xi < 8; ++xi) {
        const float v = fmaxf(acc[xi] + bias, 0.f);
        c3t[(((size_t)tb * 32 + y) * 32 + (x0 + xi)) * 128 + oc] = v;
    }
}

// ---------------------------------------------------------------------------
// K5: fconv (1x1, 128->1) + bias, hinge-loss partials, clip, mask pooling,
// v2v row-max/mean -> out[tb]. One block per tb.
// ---------------------------------------------------------------------------
__global__ __launch_bounds__(256) void k_final(
    const float* __restrict__ c3t, const float* __restrict__ fw,
    const float* __restrict__ fb, const float* __restrict__ amask,
    const float* __restrict__ pmask, const float* __restrict__ nmask,
    float* __restrict__ out, float* __restrict__ lossp)
{
    __shared__ __align__(16) float fwl[128];
    __shared__ float qmax4[32], tmax4[32];
    __shared__ float sval[1024];
    __shared__ float red[256];
    __shared__ float rowv[32], rowm[32];
    const int tid = threadIdx.x, tb = blockIdx.x;
    const int b = tb & 15;
    const float* __restrict__ tmk = (tb < BB) ? pmask : nmask;

    if (tid < 128) fwl[tid] = fw[tid];
    if (tid < 32) {
        const float* qp = amask + b * TT + 4 * tid;
        qmax4[tid] = fmaxf(fmaxf(qp[0], qp[1]), fmaxf(qp[2], qp[3]));
        const float* tp = tmk + b * TT + 4 * tid;
        tmax4[tid] = fmaxf(fmaxf(tp[0], tp[1]), fmaxf(tp[2], tp[3]));
    }
    __syncthreads();

    const float fbv = fb[0];
    float lt = 0.f;
    for (int l = 0; l < 4; ++l) {
        const int loc = tid + 256 * l;
        const int y = loc >> 5, x = loc & 31;
        const float* __restrict__ pc = c3t + ((size_t)(tb * 32 + y) * 32 + x) * 128;
        float s = fbv;
        for (int c4 = 0; c4 < 128; c4 += 4) {
            const float4 wv = *reinterpret_cast<const float4*>(&fwl[c4]);
            const float4 cv = *reinterpret_cast<const float4*>(&pc[c4]);
            s += wv.x * cv.x + wv.y * cv.y + wv.z * cv.z + wv.w * cv.w;
        }
        lt += fmaxf(0.f, -1.f - s) + fmaxf(0.f, s - 1.f);
        const float sc = fminf(fmaxf(s, -1.f), 1.f);
        const float m = qmax4[y] * tmax4[x];
        sval[loc] = (m > 0.f) ? sc : -FLT_MAX;
    }
    red[tid] = lt;
    __syncthreads();
    for (int off = 128; off > 0; off >>= 1) {
        if (tid < off) red[tid] += red[tid + off];
        __syncthreads();
    }
    if (tid == 0) lossp[tb] = red[0];

    if (tid < 32) {
        const int y = tid;
        float rm = -FLT_MAX, mm = -FLT_MAX;
        for (int x = 0; x < 32; ++x) {
            const float m = qmax4[y] * tmax4[x];
            mm = fmaxf(mm, m);
            if (m > 0.f) rm = fmaxf(rm, sval[y * 32 + x]);
        }
        rowv[y] = (mm > 0.f) ? rm : 0.f;
        rowm[y] = mm;
    }
    __syncthreads();
    if (tid == 0) {
        float num = 0.f, den = 0.f;
        for (int yy = 0; yy < 32; ++yy) { num += rowv[yy]; den += rowm[yy]; }
        out[tb] = num / den;
    }
}

__global__ void k_losssum(const float* __restrict__ lossp, float* __restrict__ out)
{
    if (threadIdx.x == 0) {
        float s = 0.f;
        for (int i = 0; i < 32; ++i) s += lossp[i];
        out[32] = s;
    }
}

// ---------------------------------------------------------------------------
extern "C" void kernel_launch(void* const* d_in, const int* in_sizes, int n_in,
                              void* d_out, int out_size, void* d_ws, size_t ws_size,
                              hipStream_t stream)
{
    (void)in_sizes; (void)n_in; (void)out_size; (void)ws_size;
    const float* anchors   = (const float*)d_in[0];
    const float* positives = (const float*)d_in[1];
    const float* negatives = (const float*)d_in[2];
    const float* amask     = (const float*)d_in[3];
    const float* pmask     = (const float*)d_in[4];
    const float* nmask     = (const float*)d_in[5];
    const float* w1 = (const float*)d_in[6];
    const float* b1 = (const float*)d_in[7];
    const float* w2 = (const float*)d_in[8];
    const float* b2 = (const float*)d_in[9];
    const float* w3 = (const float*)d_in[10];
    const float* b3 = (const float*)d_in[11];
    const float* fw = (const float*)d_in[12];
    const float* fbias = (const float*)d_in[13];

    float* ws     = (float*)d_ws;
    float* simbuf = ws;                  // 32*128*128      =  524288
    float* p1     = ws + 524288;         // 32*32*64*64     = 4194304
    float* p2     = ws + 4718592;        // 32*64*32*32     = 2097152
    float* c3t    = ws + 6815744;        // 32*32*32*128    = 4194304
    float* lossp  = ws + 11010048;       // 32
    float* outp   = (float*)d_out;       // [0..15] pos, [16..31] neg, [32] loss

    hipLaunchKernelGGL(k_f2f_mfma, dim3(8, 8, 32), dim3(192), 0, stream,
                       anchors, positives, negatives, amask, pmask, nmask, simbuf);
    hipLaunchKernelGGL(k_conv1pool, dim3(16, 32), dim3(256), 0, stream,
                       simbuf, w1, b1, p1);
    hipLaunchKernelGGL(k_conv2pool, dim3(8, 32, 32), dim3(256), 0, stream,
                       p1, w2, b2, p2);
    hipLaunchKernelGGL(k_conv3, dim3(2, 32, 32), dim3(256), 0, stream,
                       p2, w3, b3, c3t);
    hipLaunchKernelGGL(k_final, dim3(32), dim3(256), 0, stream,
                       c3t, fw, fbias, amask, pmask, nmask, outp, lossp);
    hipLaunchKernelGGL(k_losssum, dim3(1), dim3(64), 0, stream, lossp, outp);
}

// Round 5
// 461.355 us; speedup vs baseline: 1.9141x; 1.0052x over previous
//
#include <hip/hip_runtime.h>
#include <float.h>
#include <cstdint>

#define BB 16
#define TT 128
#define RG 9
#define DD 512

typedef _Float16 half8 __attribute__((ext_vector_type(8)));
typedef __fp16 fp16x2 __attribute__((ext_vector_type(2)));
typedef float f32x4 __attribute__((ext_vector_type(4)));

typedef const __attribute__((address_space(1))) void* gas_p;
typedef __attribute__((address_space(3))) void* las_p;

// ---------------------------------------------------------------------------
// K1 (MFMA + async staging): f2f chamfer similarity.
// sim[tb][i][j] = mean_o max_p dot(q[b,i,o,:], t[b,j,p,:]).
// 16x16 frame tile / block, 3 waves, o-split {3,3,3}; acc[3][9] f32x4.
// LDS: ONE f32 buffer, 288 rows (q:0..143, t:144..287) x 32 floats (128 B),
// staged via global_load_lds width=16 (async, no VGPR round-trip).
// Swizzle: physical 16B-unit u holds logical unit u^(row&7); achieved by
// pre-swizzling the per-lane GLOBAL address (LDS dest stays linear), and
// applying the same XOR on the b128 LDS reads (rule #21: both sides).
// f32->f16 conversion happens at fragment-load time via v_cvt_pkrtz.
// grid: 2048 linear blocks, XCD-bijective swizzle, tb-major it-inner order.
// ---------------------------------------------------------------------------
__device__ __forceinline__ half8 ldfrag32(const char* base, int row, int hi)
{
    const int sw = row & 7;
    const char* rp = base + row * 128;
    const float4 w0 = *reinterpret_cast<const float4*>(rp + ((((hi << 1) | 0) ^ sw) << 4));
    const float4 w1 = *reinterpret_cast<const float4*>(rp + ((((hi << 1) | 1) ^ sw) << 4));
    union { fp16x2 c[4]; half8 h8; } u;
    u.c[0] = __builtin_amdgcn_cvt_pkrtz(w0.x, w0.y);
    u.c[1] = __builtin_amdgcn_cvt_pkrtz(w0.z, w0.w);
    u.c[2] = __builtin_amdgcn_cvt_pkrtz(w1.x, w1.y);
    u.c[3] = __builtin_amdgcn_cvt_pkrtz(w1.z, w1.w);
    return u.h8;
}

__global__ __launch_bounds__(192) void k_f2f_mfma(
    const float* __restrict__ anchors,
    const float* __restrict__ positives,
    const float* __restrict__ negatives,
    const float* __restrict__ amask,
    const float* __restrict__ pmask,
    const float* __restrict__ nmask,
    float* __restrict__ simbuf)
{
    __shared__ __align__(16) char lds[36864];   // 288 rows x 128 B

    const int tid = threadIdx.x;
    const int lane = tid & 63, wave = tid >> 6;
    const int lo = lane & 15, hi = lane >> 4;

    // XCD-bijective block swizzle: hw -> L, tb-major, it-inner, jt-innermost
    const int hw = blockIdx.x;
    const int L  = (hw & 7) * 256 + (hw >> 3);
    const int tb = L >> 6;
    const int it = (L >> 3) & 7;
    const int jt = L & 7;

    const int b = tb & 15;
    const float* __restrict__ tptr = (tb < BB) ? positives : negatives;
    const float* __restrict__ tmk  = (tb < BB) ? pmask : nmask;
    const int i0 = it * 16, j0 = jt * 16;
    const float* __restrict__ qsrc = anchors + ((size_t)(b * TT + i0)) * RG * DD;
    const float* __restrict__ tsrc = tptr    + ((size_t)(b * TT + j0)) * RG * DD;

    f32x4 acc[3][9];
#pragma unroll
    for (int oi = 0; oi < 3; ++oi)
#pragma unroll
        for (int p = 0; p < 9; ++p)
            acc[oi][p] = (f32x4){0.f, 0.f, 0.f, 0.f};

    const int o0 = wave * 3;
    const int lrow = lane >> 3;                  // 0..7 (row within 8-row strip)
    const int up   = (lane & 7) ^ lrow;          // swizzled logical 16B unit

    for (int kc = 0; kc < DD; kc += 32) {
        __syncthreads();                         // prev chunk's reads done
#pragma unroll
        for (int i = 0; i < 12; ++i) {
            const int f   = wave * 12 + i;       // 0..35 (1-KB strip index)
            const int row = f * 8 + lrow;        // 0..287
            const int tsel = row >= 144;
            const int r   = row - (tsel ? 144 : 0);
            const int o   = r >> 4, il = r & 15;
            const float* src = tsel ? tsrc : qsrc;
            const float* g = src + (((size_t)(il * RG + o)) << 9) + kc + (up << 2);
            __builtin_amdgcn_global_load_lds((gas_p)g, (las_p)(lds + (f << 10)), 16, 0, 0);
        }
        __syncthreads();                         // compiler drains vmcnt here

        const half8 a0 = ldfrag32(lds, (o0 + 0) * 16 + lo, hi);
        const half8 a1 = ldfrag32(lds, (o0 + 1) * 16 + lo, hi);
        const half8 a2 = ldfrag32(lds, (o0 + 2) * 16 + lo, hi);
#pragma unroll
        for (int p = 0; p < 9; ++p) {
            const half8 bf = ldfrag32(lds, 144 + p * 16 + lo, hi);
            acc[0][p] = __builtin_amdgcn_mfma_f32_16x16x32_f16(a0, bf, acc[0][p], 0, 0, 0);
            acc[1][p] = __builtin_amdgcn_mfma_f32_16x16x32_f16(a1, bf, acc[1][p], 0, 0, 0);
            acc[2][p] = __builtin_amdgcn_mfma_f32_16x16x32_f16(a2, bf, acc[2][p], 0, 0, 0);
        }
    }

    // per-lane: sum over my 3 o of (max over 9 p)
    f32x4 part = {0.f, 0.f, 0.f, 0.f};
#pragma unroll
    for (int oi = 0; oi < 3; ++oi) {
        f32x4 m = acc[oi][0];
#pragma unroll
        for (int p = 1; p < 9; ++p) {
            m[0] = fmaxf(m[0], acc[oi][p][0]);
            m[1] = fmaxf(m[1], acc[oi][p][1]);
            m[2] = fmaxf(m[2], acc[oi][p][2]);
            m[3] = fmaxf(m[3], acc[oi][p][3]);
        }
        part[0] += m[0]; part[1] += m[1]; part[2] += m[2]; part[3] += m[3];
    }

    // cross-wave sum (3 waves) via LDS (safe: barrier before overwrite)
    __syncthreads();
    float* red = reinterpret_cast<float*>(lds);
    *reinterpret_cast<f32x4*>(red + (size_t)(wave * 64 + lane) * 4) = part;
    __syncthreads();
    if (wave == 0) {
        const f32x4 t0 = *reinterpret_cast<const f32x4*>(red + (size_t)lane * 4);
        const f32x4 t1 = *reinterpret_cast<const f32x4*>(red + (size_t)(64 + lane) * 4);
        const f32x4 t2 = *reinterpret_cast<const f32x4*>(red + (size_t)(128 + lane) * 4);
        const int j = j0 + lo;
        const float tm = tmk[b * TT + j];
#pragma unroll
        for (int r = 0; r < 4; ++r) {
            const int i = i0 + hi * 4 + r;
            const float mk = amask[b * TT + i] * tm;
            const float s = (t0[r] + t1[r] + t2[r]) * (1.f / 9.f);
            simbuf[((size_t)tb * TT + i) * TT + j] = (mk > 0.f) ? s : 0.f;
        }
    }
}

// ---------------------------------------------------------------------------
// K2: conv1(1->32, 3x3, pad1) + bias + relu + maxpool2.
// ---------------------------------------------------------------------------
__global__ __launch_bounds__(256) void k_conv1pool(
    const float* __restrict__ simbuf, const float* __restrict__ w1,
    const float* __restrict__ b1, float* __restrict__ p1)
{
    __shared__ float wl[288];
    __shared__ float bl[32];
    const int tid = threadIdx.x;
    const int tb = blockIdx.y, yg = blockIdx.x;
    for (int e = tid; e < 288; e += 256) wl[e] = w1[e];
    if (tid < 32)  bl[tid] = b1[tid];
    __syncthreads();

    const int y = yg * 4 + (tid >> 6);
    const int x = tid & 63;
    const float* __restrict__ sp = simbuf + (size_t)tb * TT * TT;

    float iv[4][4];
#pragma unroll
    for (int r = 0; r < 4; ++r) {
        const int gy = 2 * y - 1 + r;
#pragma unroll
        for (int c = 0; c < 4; ++c) {
            const int gx = 2 * x - 1 + c;
            iv[r][c] = (gy >= 0 && gy < TT && gx >= 0 && gx < TT)
                           ? sp[gy * TT + gx] : 0.f;
        }
    }
    for (int oc = 0; oc < 32; ++oc) {
        float a00 = 0.f, a01 = 0.f, a10 = 0.f, a11 = 0.f;
#pragma unroll
        for (int rr = 0; rr < 3; ++rr)
#pragma unroll
            for (int cc = 0; cc < 3; ++cc) {
                const float w = wl[oc * 9 + rr * 3 + cc];
                a00 = fmaf(w, iv[rr][cc],         a00);
                a01 = fmaf(w, iv[rr][cc + 1],     a01);
                a10 = fmaf(w, iv[rr + 1][cc],     a10);
                a11 = fmaf(w, iv[rr + 1][cc + 1], a11);
            }
        float m = fmaxf(fmaxf(a00, a01), fmaxf(a10, a11)) + bl[oc];
        m = fmaxf(m, 0.f);
        p1[(((size_t)tb * 32 + oc) * 64 + y) * 64 + x] = m;
    }
}

// ---------------------------------------------------------------------------
// K3: conv2(32->64, 3x3, pad1) + bias + relu + maxpool2.
// ---------------------------------------------------------------------------
__global__ __launch_bounds__(256) void k_conv2pool(
    const float* __restrict__ p1, const float* __restrict__ w2,
    const float* __restrict__ b2, float* __restrict__ p2)
{
    __shared__ float wl[64 * 73];
    __shared__ float intile[8 * 40];
    const int tid = threadIdx.x;
    const int xg = blockIdx.x, y = blockIdx.y, tb = blockIdx.z;
    const int oc = tid & 63, xs = tid >> 6;
    const int x = xg * 4 + xs;

    float acc4[4] = {0.f, 0.f, 0.f, 0.f};

    for (int icc = 0; icc < 4; ++icc) {
        for (int e = tid; e < 4608; e += 256) {
            const int oc_ = e / 72, rem = e - oc_ * 72;
            wl[oc_ * 73 + rem] = w2[oc_ * 288 + icc * 72 + rem];
        }
        for (int e = tid; e < 320; e += 256) {
            const int ic_ = e / 40, rem = e - ic_ * 40;
            const int r = rem / 10, c = rem - r * 10;
            const int gy = 2 * y - 1 + r, gx = xg * 8 - 1 + c;
            float v = 0.f;
            if (gy >= 0 && gy < 64 && gx >= 0 && gx < 64)
                v = p1[(((size_t)tb * 32 + icc * 8 + ic_) * 64 + gy) * 64 + gx];
            intile[e] = v;
        }
        __syncthreads();
#pragma unroll
        for (int ic = 0; ic < 8; ++ic) {
            float iv[16];
#pragma unroll
            for (int r = 0; r < 4; ++r)
#pragma unroll
                for (int c = 0; c < 4; ++c)
                    iv[r * 4 + c] = intile[ic * 40 + r * 10 + 2 * xs + c];
            float w9[9];
#pragma unroll
            for (int t9 = 0; t9 < 9; ++t9)
                w9[t9] = wl[oc * 73 + ic * 9 + t9];
#pragma unroll
            for (int rr = 0; rr < 3; ++rr)
#pragma unroll
                for (int cc = 0; cc < 3; ++cc) {
                    const float w = w9[rr * 3 + cc];
                    acc4[0] = fmaf(w, iv[rr * 4 + cc],           acc4[0]);
                    acc4[1] = fmaf(w, iv[rr * 4 + cc + 1],       acc4[1]);
                    acc4[2] = fmaf(w, iv[(rr + 1) * 4 + cc],     acc4[2]);
                    acc4[3] = fmaf(w, iv[(rr + 1) * 4 + cc + 1], acc4[3]);
                }
        }
        __syncthreads();
    }
    float m = fmaxf(fmaxf(acc4[0], acc4[1]), fmaxf(acc4[2], acc4[3])) + b2[oc];
    m = fmaxf(m, 0.f);
    p2[(((size_t)tb * 64 + oc) * 32 + y) * 32 + x] = m;
}

// ---------------------------------------------------------------------------
// K4: conv3(64->128, 3x3, pad1) + bias + relu. Output [tb][y][x][oc].
// ---------------------------------------------------------------------------
__global__ __launch_bounds__(256) void k_conv3(
    const float* __restrict__ p2, const float* __restrict__ w3,
    const float* __restrict__ b3, float* __restrict__ c3t)
{
    __shared__ float wl[128 * 73];
    __shared__ float intile[8 * 54];
    const int tid = threadIdx.x;
    const int xg = blockIdx.x, y = blockIdx.y, tb = blockIdx.z;
    const int oc = tid & 127, xh = tid >> 7;
    const int x0 = xg * 16 + xh * 8;

    float acc[8];
#pragma unroll
    for (int i = 0; i < 8; ++i) acc[i] = 0.f;

    for (int icc = 0; icc < 8; ++icc) {
        for (int e = tid; e < 9216; e += 256) {
            const int oc_ = e / 72, rem = e - oc_ * 72;
            wl[oc_ * 73 + rem] = w3[oc_ * 576 + icc * 72 + rem];
        }
        for (int e = tid; e < 432; e += 256) {
            const int ic_ = e / 54, rem = e - ic_ * 54;
            const int r = rem / 18, c = rem - r * 18;
            const int gy = y - 1 + r, gx = xg * 16 - 1 + c;
            float v = 0.f;
            if (gy >= 0 && gy < 32 && gx >= 0 && gx < 32)
                v = p2[(((size_t)tb * 64 + icc * 8 + ic_) * 32 + gy) * 32 + gx];
            intile[e] = v;
        }
        __syncthreads();
#pragma unroll
        for (int ic = 0; ic < 8; ++ic) {
            float w9[9];
#pragma unroll
            for (int t9 = 0; t9 < 9; ++t9)
                w9[t9] = wl[oc * 73 + ic * 9 + t9];
            float irow[3][10];
#pragma unroll
            for (int r = 0; r < 3; ++r)
#pragma unroll
                for (int c = 0; c < 10; ++c)
                    irow[r][c] = intile[ic * 54 + r * 18 + xh * 8 + c];
#pragma unroll
            for (int xi = 0; xi < 8; ++xi)
#pragma unroll
                for (int rr = 0; rr < 3; ++rr)
#pragma unroll
                    for (int cc = 0; cc < 3; ++cc)
                        acc[xi] = fmaf(w9[rr * 3 + cc], irow[rr][xi + cc], acc[xi]);
        }
        __syncthreads();
    }
    const float bias = b3[oc];
#pragma unroll
    for (int xi = 0; xi < 8; ++xi) {
        const float v = fmaxf(acc[xi] + bias, 0.f);
        c3t[(((size_t)tb * 32 + y) * 32 + (x0 + xi)) * 128 + oc] = v;
    }
}

// ---------------------------------------------------------------------------
// K5: fconv (1x1, 128->1) + bias, hinge-loss partials, clip, mask pooling,
// v2v row-max/mean -> out[tb]. One block per tb.
// ---------------------------------------------------------------------------
__global__ __launch_bounds__(256) void k_final(
    const float* __restrict__ c3t, const float* __restrict__ fw,
    const float* __restrict__ fb, const float* __restrict__ amask,
    const float* __restrict__ pmask, const float* __restrict__ nmask,
    float* __restrict__ out, float* __restrict__ lossp)
{
    __shared__ __align__(16) float fwl[128];
    __shared__ float qmax4[32], tmax4[32];
    __shared__ float sval[1024];
    __shared__ float red[256];
    __shared__ float rowv[32], rowm[32];
    const int tid = threadIdx.x, tb = blockIdx.x;
    const int b = tb & 15;
    const float* __restrict__ tmk = (tb < BB) ? pmask : nmask;

    if (tid < 128) fwl[tid] = fw[tid];
    if (tid < 32) {
        const float* qp = amask + b * TT + 4 * tid;
        qmax4[tid] = fmaxf(fmaxf(qp[0], qp[1]), fmaxf(qp[2], qp[3]));
        const float* tp = tmk + b * TT + 4 * tid;
        tmax4[tid] = fmaxf(fmaxf(tp[0], tp[1]), fmaxf(tp[2], tp[3]));
    }
    __syncthreads();

    const float fbv = fb[0];
    float lt = 0.f;
    for (int l = 0; l < 4; ++l) {
        const int loc = tid + 256 * l;
        const int y = loc >> 5, x = loc & 31;
        const float* __restrict__ pc = c3t + ((size_t)(tb * 32 + y) * 32 + x) * 128;
        float s = fbv;
        for (int c4 = 0; c4 < 128; c4 += 4) {
            const float4 wv = *reinterpret_cast<const float4*>(&fwl[c4]);
            const float4 cv = *reinterpret_cast<const float4*>(&pc[c4]);
            s += wv.x * cv.x + wv.y * cv.y + wv.z * cv.z + wv.w * cv.w;
        }
        lt += fmaxf(0.f, -1.f - s) + fmaxf(0.f, s - 1.f);
        const float sc = fminf(fmaxf(s, -1.f), 1.f);
        const float m = qmax4[y] * tmax4[x];
        sval[loc] = (m > 0.f) ? sc : -FLT_MAX;
    }
    red[tid] = lt;
    __syncthreads();
    for (int off = 128; off > 0; off >>= 1) {
        if (tid < off) red[tid] += red[tid + off];
        __syncthreads();
    }
    if (tid == 0) lossp[tb] = red[0];

    if (tid < 32) {
        const int y = tid;
        float rm = -FLT_MAX, mm = -FLT_MAX;
        for (int x = 0; x < 32; ++x) {
            const float m = qmax4[y] * tmax4[x];
            mm = fmaxf(mm, m);
            if (m > 0.f) rm = fmaxf(rm, sval[y * 32 + x]);
        }
        rowv[y] = (mm > 0.f) ? rm : 0.f;
        rowm[y] = mm;
    }
    __syncthreads();
    if (tid == 0) {
        float num = 0.f, den = 0.f;
        for (int yy = 0; yy < 32; ++yy) { num += rowv[yy]; den += rowm[yy]; }
        out[tb] = num / den;
    }
}

__global__ void k_losssum(const float* __restrict__ lossp, float* __restrict__ out)
{
    if (threadIdx.x == 0) {
        float s = 0.f;
        for (int i = 0; i < 32; ++i) s += lossp[i];
        out[32] = s;
    }
}

// ---------------------------------------------------------------------------
extern "C" void kernel_launch(void* const* d_in, const int* in_sizes, int n_in,
                              void* d_out, int out_size, void* d_ws, size_t ws_size,
                              hipStream_t stream)
{
    (void)in_sizes; (void)n_in; (void)out_size; (void)ws_size;
    const float* anchors   = (const float*)d_in[0];
    const float* positives = (const float*)d_in[1];
    const float* negatives = (const float*)d_in[2];
    const float* amask     = (const float*)d_in[3];
    const float* pmask     = (const float*)d_in[4];
    const float* nmask     = (const float*)d_in[5];
    const float* w1 = (const float*)d_in[6];
    const float* b1 = (const float*)d_in[7];
    const float* w2 = (const float*)d_in[8];
    const float* b2 = (const float*)d_in[9];
    const float* w3 = (const float*)d_in[10];
    const float* b3 = (const float*)d_in[11];
    const float* fw = (const float*)d_in[12];
    const float* fbias = (const float*)d_in[13];

    float* ws     = (float*)d_ws;
    float* simbuf = ws;                  // 32*128*128      =  524288
    float* p1     = ws + 524288;         // 32*32*64*64     = 4194304
    float* p2     = ws + 4718592;        // 32*64*32*32     = 2097152
    float* c3t    = ws + 6815744;        // 32*32*32*128    = 4194304
    float* lossp  = ws + 11010048;       // 32
    float* outp   = (float*)d_out;       // [0..15] pos, [16..31] neg, [32] loss

    hipLaunchKernelGGL(k_f2f_mfma, dim3(2048), dim3(192), 0, stream,
                       anchors, positives, negatives, amask, pmask, nmask, simbuf);
    hipLaunchKernelGGL(k_conv1pool, dim3(16, 32), dim3(256), 0, stream,
                       simbuf, w1, b1, p1);
    hipLaunchKernelGGL(k_conv2pool, dim3(8, 32, 32), dim3(256), 0, stream,
                       p1, w2, b2, p2);
    hipLaunchKernelGGL(k_conv3, dim3(2, 32, 32), dim3(256), 0, stream,
                       p2, w3, b3, c3t);
    hipLaunchKernelGGL(k_final, dim3(32), dim3(256), 0, stream,
                       c3t, fw, fbias, amask, pmask, nmask, outp, lossp);
    hipLaunchKernelGGL(k_losssum, dim3(1), dim3(64), 0, stream, lossp, outp);
}

// Round 7
// 458.244 us; speedup vs baseline: 1.9271x; 1.0068x over previous
//
#include <hip/hip_runtime.h>
#include <float.h>
#include <cstdint>

#define BB 16
#define TT 128
#define RG 9
#define DD 512

typedef _Float16 half8 __attribute__((ext_vector_type(8)));
typedef float f32x4 __attribute__((ext_vector_type(4)));

// ---------------------------------------------------------------------------
// K0: one-time f32 -> f16 (RNE) conversion of the three feature tensors.
// Each tensor: B*T*R*D = 9,437,184 elements = 4608 blocks x 256 thr x 8 elem.
// ---------------------------------------------------------------------------
__global__ __launch_bounds__(256) void k_cvt16(
    const float* __restrict__ a, const float* __restrict__ p,
    const float* __restrict__ n,
    _Float16* __restrict__ da, _Float16* __restrict__ dp,
    _Float16* __restrict__ dn)
{
    const int which = blockIdx.y;
    const float* __restrict__ s = (which == 0) ? a : (which == 1) ? p : n;
    _Float16* __restrict__ d    = (which == 0) ? da : (which == 1) ? dp : dn;
    const size_t i = (size_t)blockIdx.x * 256 + threadIdx.x;
    const float4 v0 = reinterpret_cast<const float4*>(s)[2 * i];
    const float4 v1 = reinterpret_cast<const float4*>(s)[2 * i + 1];
    half8 h;
    h[0] = (_Float16)v0.x; h[1] = (_Float16)v0.y;
    h[2] = (_Float16)v0.z; h[3] = (_Float16)v0.w;
    h[4] = (_Float16)v1.x; h[5] = (_Float16)v1.y;
    h[6] = (_Float16)v1.z; h[7] = (_Float16)v1.w;
    *reinterpret_cast<half8*>(d + i * 8) = h;
}

// ---------------------------------------------------------------------------
// K1 (MFMA, LDS-free, barrier-free): f2f chamfer similarity from f16 data.
// sim[tb][i][j] = mean_o max_p dot(q[b,i,o,:], t[b,j,p,:]).
// Each lane loads MFMA fragments DIRECTLY from global: one 16-B dwordx4 is a
// complete 8-f16 fragment (row = lo, k-slice = hi*8), the round-3-verified
// mapping. Per 32-k chunk per wave: 12 loads + 27 MFMA, no barriers, no LDS,
// no cvt. L1/L2 absorb the q(x8 blocks)/t(x3 waves) re-reads; the XCD swizzle
// (4 tb per XCD, it-mid, jt-inner) keeps the working set L2-resident.
// grid 2048 linear, block 192 (3 waves, o-split {3,3,3}).
// ---------------------------------------------------------------------------
__global__ __launch_bounds__(192) void k_f2f_mfma(
    const _Float16* __restrict__ q16,
    const _Float16* __restrict__ p16,
    const _Float16* __restrict__ n16,
    const float* __restrict__ amask,
    const float* __restrict__ pmask,
    const float* __restrict__ nmask,
    float* __restrict__ simbuf)
{
    __shared__ float red[768];

    const int tid = threadIdx.x;
    const int lane = tid & 63, wave = tid >> 6;
    const int lo = lane & 15, hi = lane >> 4;

    // XCD-bijective block swizzle: tb-major, it-mid, jt-inner per XCD
    const int hw = blockIdx.x;
    const int L  = (hw & 7) * 256 + (hw >> 3);
    const int tb = L >> 6;
    const int it = (L >> 3) & 7;
    const int jt = L & 7;

    const int b = tb & 15;
    const _Float16* __restrict__ tptr = (tb < BB) ? p16 : n16;
    const float* __restrict__ tmk  = (tb < BB) ? pmask : nmask;
    const int i0 = it * 16, j0 = jt * 16;

    // per-lane fragment row pointers (already offset by hi*8 in k)
    const _Float16* __restrict__ qrow =
        q16 + (size_t)((b * TT + i0 + lo) * RG) * DD + hi * 8;
    const _Float16* __restrict__ trow =
        tptr + (size_t)((b * TT + j0 + lo) * RG) * DD + hi * 8;

    const int o0 = wave * 3;

    f32x4 acc[3][9];
#pragma unroll
    for (int oi = 0; oi < 3; ++oi)
#pragma unroll
        for (int p = 0; p < 9; ++p)
            acc[oi][p] = (f32x4){0.f, 0.f, 0.f, 0.f};

    for (int kc = 0; kc < DD; kc += 32) {
        const half8 a0 = *reinterpret_cast<const half8*>(qrow + (size_t)(o0 + 0) * DD + kc);
        const half8 a1 = *reinterpret_cast<const half8*>(qrow + (size_t)(o0 + 1) * DD + kc);
        const half8 a2 = *reinterpret_cast<const half8*>(qrow + (size_t)(o0 + 2) * DD + kc);
#pragma unroll
        for (int p = 0; p < 9; ++p) {
            const half8 bf = *reinterpret_cast<const half8*>(trow + (size_t)p * DD + kc);
            acc[0][p] = __builtin_amdgcn_mfma_f32_16x16x32_f16(a0, bf, acc[0][p], 0, 0, 0);
            acc[1][p] = __builtin_amdgcn_mfma_f32_16x16x32_f16(a1, bf, acc[1][p], 0, 0, 0);
            acc[2][p] = __builtin_amdgcn_mfma_f32_16x16x32_f16(a2, bf, acc[2][p], 0, 0, 0);
        }
    }

    // per-lane: sum over my 3 o of (max over 9 p)
    f32x4 part = {0.f, 0.f, 0.f, 0.f};
#pragma unroll
    for (int oi = 0; oi < 3; ++oi) {
        f32x4 m = acc[oi][0];
#pragma unroll
        for (int p = 1; p < 9; ++p) {
            m[0] = fmaxf(m[0], acc[oi][p][0]);
            m[1] = fmaxf(m[1], acc[oi][p][1]);
            m[2] = fmaxf(m[2], acc[oi][p][2]);
            m[3] = fmaxf(m[3], acc[oi][p][3]);
        }
        part[0] += m[0]; part[1] += m[1]; part[2] += m[2]; part[3] += m[3];
    }

    // cross-wave sum (3 waves)
    *reinterpret_cast<f32x4*>(red + (size_t)(wave * 64 + lane) * 4) = part;
    __syncthreads();
    if (wave == 0) {
        const f32x4 t0 = *reinterpret_cast<const f32x4*>(red + (size_t)lane * 4);
        const f32x4 t1 = *reinterpret_cast<const f32x4*>(red + (size_t)(64 + lane) * 4);
        const f32x4 t2 = *reinterpret_cast<const f32x4*>(red + (size_t)(128 + lane) * 4);
        const int j = j0 + lo;
        const float tm = tmk[b * TT + j];
#pragma unroll
        for (int r = 0; r < 4; ++r) {
            const int i = i0 + hi * 4 + r;
            const float mk = amask[b * TT + i] * tm;
            const float s = (t0[r] + t1[r] + t2[r]) * (1.f / 9.f);
            simbuf[((size_t)tb * TT + i) * TT + j] = (mk > 0.f) ? s : 0.f;
        }
    }
}

// ---------------------------------------------------------------------------
// K2: conv1(1->32, 3x3, pad1) + bias + relu + maxpool2.
// ---------------------------------------------------------------------------
__global__ __launch_bounds__(256) void k_conv1pool(
    const float* __restrict__ simbuf, const float* __restrict__ w1,
    const float* __restrict__ b1, float* __restrict__ p1)
{
    __shared__ float wl[288];
    __shared__ float bl[32];
    const int tid = threadIdx.x;
    const int tb = blockIdx.y, yg = blockIdx.x;
    for (int e = tid; e < 288; e += 256) wl[e] = w1[e];
    if (tid < 32)  bl[tid] = b1[tid];
    __syncthreads();

    const int y = yg * 4 + (tid >> 6);
    const int x = tid & 63;
    const float* __restrict__ sp = simbuf + (size_t)tb * TT * TT;

    float iv[4][4];
#pragma unroll
    for (int r = 0; r < 4; ++r) {
        const int gy = 2 * y - 1 + r;
#pragma unroll
        for (int c = 0; c < 4; ++c) {
            const int gx = 2 * x - 1 + c;
            iv[r][c] = (gy >= 0 && gy < TT && gx >= 0 && gx < TT)
                           ? sp[gy * TT + gx] : 0.f;
        }
    }
    for (int oc = 0; oc < 32; ++oc) {
        float a00 = 0.f, a01 = 0.f, a10 = 0.f, a11 = 0.f;
#pragma unroll
        for (int rr = 0; rr < 3; ++rr)
#pragma unroll
            for (int cc = 0; cc < 3; ++cc) {
                const float w = wl[oc * 9 + rr * 3 + cc];
                a00 = fmaf(w, iv[rr][cc],         a00);
                a01 = fmaf(w, iv[rr][cc + 1],     a01);
                a10 = fmaf(w, iv[rr + 1][cc],     a10);
                a11 = fmaf(w, iv[rr + 1][cc + 1], a11);
            }
        float m = fmaxf(fmaxf(a00, a01), fmaxf(a10, a11)) + bl[oc];
        m = fmaxf(m, 0.f);
        p1[(((size_t)tb * 32 + oc) * 64 + y) * 64 + x] = m;
    }
}

// ---------------------------------------------------------------------------
// K3: conv2(32->64, 3x3, pad1) + bias + relu + maxpool2.
// ---------------------------------------------------------------------------
__global__ __launch_bounds__(256) void k_conv2pool(
    const float* __restrict__ p1, const float* __restrict__ w2,
    const float* __restrict__ b2, float* __restrict__ p2)
{
    __shared__ float wl[64 * 73];
    __shared__ float intile[8 * 40];
    const int tid = threadIdx.x;
    const int xg = blockIdx.x, y = blockIdx.y, tb = blockIdx.z;
    const int oc = tid & 63, xs = tid >> 6;
    const int x = xg * 4 + xs;

    float acc4[4] = {0.f, 0.f, 0.f, 0.f};

    for (int icc = 0; icc < 4; ++icc) {
        for (int e = tid; e < 4608; e += 256) {
            const int oc_ = e / 72, rem = e - oc_ * 72;
            wl[oc_ * 73 + rem] = w2[oc_ * 288 + icc * 72 + rem];
        }
        for (int e = tid; e < 320; e += 256) {
            const int ic_ = e / 40, rem = e - ic_ * 40;
            const int r = rem / 10, c = rem - r * 10;
            const int gy = 2 * y - 1 + r, gx = xg * 8 - 1 + c;
            float v = 0.f;
            if (gy >= 0 && gy < 64 && gx >= 0 && gx < 64)
                v = p1[(((size_t)tb * 32 + icc * 8 + ic_) * 64 + gy) * 64 + gx];
            intile[e] = v;
        }
        __syncthreads();
#pragma unroll
        for (int ic = 0; ic < 8; ++ic) {
            float iv[16];
#pragma unroll
            for (int r = 0; r < 4; ++r)
#pragma unroll
                for (int c = 0; c < 4; ++c)
                    iv[r * 4 + c] = intile[ic * 40 + r * 10 + 2 * xs + c];
            float w9[9];
#pragma unroll
            for (int t9 = 0; t9 < 9; ++t9)
                w9[t9] = wl[oc * 73 + ic * 9 + t9];
#pragma unroll
            for (int rr = 0; rr < 3; ++rr)
#pragma unroll
                for (int cc = 0; cc < 3; ++cc) {
                    const float w = w9[rr * 3 + cc];
                    acc4[0] = fmaf(w, iv[rr * 4 + cc],           acc4[0]);
                    acc4[1] = fmaf(w, iv[rr * 4 + cc + 1],       acc4[1]);
                    acc4[2] = fmaf(w, iv[(rr + 1) * 4 + cc],     acc4[2]);
                    acc4[3] = fmaf(w, iv[(rr + 1) * 4 + cc + 1], acc4[3]);
                }
        }
        __syncthreads();
    }
    float m = fmaxf(fmaxf(acc4[0], acc4[1]), fmaxf(acc4[2], acc4[3])) + b2[oc];
    m = fmaxf(m, 0.f);
    p2[(((size_t)tb * 64 + oc) * 32 + y) * 32 + x] = m;
}

// ---------------------------------------------------------------------------
// K4: conv3(64->128, 3x3, pad1) + bias + relu. Output [tb][y][x][oc].
// ---------------------------------------------------------------------------
__global__ __launch_bounds__(256) void k_conv3(
    const float* __restrict__ p2, const float* __restrict__ w3,
    const float* __restrict__ b3, float* __restrict__ c3t)
{
    __shared__ float wl[128 * 73];
    __shared__ float intile[8 * 54];
    const int tid = threadIdx.x;
    const int xg = blockIdx.x, y = blockIdx.y, tb = blockIdx.z;
    const int oc = tid & 127, xh = tid >> 7;
    const int x0 = xg * 16 + xh * 8;

    float acc[8];
#pragma unroll
    for (int i = 0; i < 8; ++i) acc[i] = 0.f;

    for (int icc = 0; icc < 8; ++icc) {
        for (int e = tid; e < 9216; e += 256) {
            const int oc_ = e / 72, rem = e - oc_ * 72;
            wl[oc_ * 73 + rem] = w3[oc_ * 576 + icc * 72 + rem];
        }
        for (int e = tid; e < 432; e += 256) {
            const int ic_ = e / 54, rem = e - ic_ * 54;
            const int r = rem / 18, c = rem - r * 18;
            const int gy = y - 1 + r, gx = xg * 16 - 1 + c;
            float v = 0.f;
            if (gy >= 0 && gy < 32 && gx >= 0 && gx < 32)
                v = p2[(((size_t)tb * 64 + icc * 8 + ic_) * 32 + gy) * 32 + gx];
            intile[e] = v;
        }
        __syncthreads();
#pragma unroll
        for (int ic = 0; ic < 8; ++ic) {
            float w9[9];
#pragma unroll
            for (int t9 = 0; t9 < 9; ++t9)
                w9[t9] = wl[oc * 73 + ic * 9 + t9];
            float irow[3][10];
#pragma unroll
            for (int r = 0; r < 3; ++r)
#pragma unroll
                for (int c = 0; c < 10; ++c)
                    irow[r][c] = intile[ic * 54 + r * 18 + xh * 8 + c];
#pragma unroll
            for (int xi = 0; xi < 8; ++xi)
#pragma unroll
                for (int rr = 0; rr < 3; ++rr)
#pragma unroll
                    for (int cc = 0; cc < 3; ++cc)
                        acc[xi] = fmaf(w9[rr * 3 + cc], irow[rr][xi + cc], acc[xi]);
        }
        __syncthreads();
    }
    const float bias = b3[oc];
#pragma unroll
    for (int xi = 0; xi < 8; ++xi) {
        const float v = fmaxf(acc[xi] + bias, 0.f);
        c3t[(((size_t)tb * 32 + y) * 32 + (x0 + xi)) * 128 + oc] = v;
    }
}

// ---------------------------------------------------------------------------
// K5: fconv (1x1, 128->1) + bias, hinge-loss partials, clip, mask pooling,
// v2v row-max/mean -> out[tb]. One block per tb.
// ---------------------------------------------------------------------------
__global__ __launch_bounds__(256) void k_final(
    const float* __restrict__ c3t, const float* __restrict__ fw,
    const float* __restrict__ fb, const float* __restrict__ amask,
    const float* __restrict__ pmask, const float* __restrict__ nmask,
    float* __restrict__ out, float* __restrict__ lossp)
{
    __shared__ __align__(16) float fwl[128];
    __shared__ float qmax4[32], tmax4[32];
    __shared__ float sval[1024];
    __shared__ float red[256];
    __shared__ float rowv[32], rowm[32];
    const int tid = threadIdx.x, tb = blockIdx.x;
    const int b = tb & 15;
    const float* __restrict__ tmk = (tb < BB) ? pmask : nmask;

    if (tid < 128) fwl[tid] = fw[tid];
    if (tid < 32) {
        const float* qp = amask + b * TT + 4 * tid;
        qmax4[tid] = fmaxf(fmaxf(qp[0], qp[1]), fmaxf(qp[2], qp[3]));
        const float* tp = tmk + b * TT + 4 * tid;
        tmax4[tid] = fmaxf(fmaxf(tp[0], tp[1]), fmaxf(tp[2], tp[3]));
    }
    __syncthreads();

    const float fbv = fb[0];
    float lt = 0.f;
    for (int l = 0; l < 4; ++l) {
        const int loc = tid + 256 * l;
        const int y = loc >> 5, x = loc & 31;
        const float* __restrict__ pc = c3t + ((size_t)(tb * 32 + y) * 32 + x) * 128;
        float s = fbv;
        for (int c4 = 0; c4 < 128; c4 += 4) {
            const float4 wv = *reinterpret_cast<const float4*>(&fwl[c4]);
            const float4 cv = *reinterpret_cast<const float4*>(&pc[c4]);
            s += wv.x * cv.x + wv.y * cv.y + wv.z * cv.z + wv.w * cv.w;
        }
        lt += fmaxf(0.f, -1.f - s) + fmaxf(0.f, s - 1.f);
        const float sc = fminf(fmaxf(s, -1.f), 1.f);
        const float m = qmax4[y] * tmax4[x];
        sval[loc] = (m > 0.f) ? sc : -FLT_MAX;
    }
    red[tid] = lt;
    __syncthreads();
    for (int off = 128; off > 0; off >>= 1) {
        if (tid < off) red[tid] += red[tid + off];
        __syncthreads();
    }
    if (tid == 0) lossp[tb] = red[0];

    if (tid < 32) {
        const int y = tid;
        float rm = -FLT_MAX, mm = -FLT_MAX;
        for (int x = 0; x < 32; ++x) {
            const float m = qmax4[y] * tmax4[x];
            mm = fmaxf(mm, m);
            if (m > 0.f) rm = fmaxf(rm, sval[y * 32 + x]);
        }
        rowv[y] = (mm > 0.f) ? rm : 0.f;
        rowm[y] = mm;
    }
    __syncthreads();
    if (tid == 0) {
        float num = 0.f, den = 0.f;
        for (int yy = 0; yy < 32; ++yy) { num += rowv[yy]; den += rowm[yy]; }
        out[tb] = num / den;
    }
}

__global__ void k_losssum(const float* __restrict__ lossp, float* __restrict__ out)
{
    if (threadIdx.x == 0) {
        float s = 0.f;
        for (int i = 0; i < 32; ++i) s += lossp[i];
        out[32] = s;
    }
}

// ---------------------------------------------------------------------------
extern "C" void kernel_launch(void* const* d_in, const int* in_sizes, int n_in,
                              void* d_out, int out_size, void* d_ws, size_t ws_size,
                              hipStream_t stream)
{
    (void)in_sizes; (void)n_in; (void)out_size; (void)ws_size;
    const float* anchors   = (const float*)d_in[0];
    const float* positives = (const float*)d_in[1];
    const float* negatives = (const float*)d_in[2];
    const float* amask     = (const float*)d_in[3];
    const float* pmask     = (const float*)d_in[4];
    const float* nmask     = (const float*)d_in[5];
    const float* w1 = (const float*)d_in[6];
    const float* b1 = (const float*)d_in[7];
    const float* w2 = (const float*)d_in[8];
    const float* b2 = (const float*)d_in[9];
    const float* w3 = (const float*)d_in[10];
    const float* b3 = (const float*)d_in[11];
    const float* fw = (const float*)d_in[12];
    const float* fbias = (const float*)d_in[13];

    // Workspace layout. The f16 feature copies [524288, 14680064) are DEAD
    // after K1; p1/p2/c3t/lossp re-use that region from K2 onward
    // (stream-ordered, no temporal overlap). Peak use: 58.7 MB.
    float* ws     = (float*)d_ws;
    float* simbuf = ws;                  // [0, 524288)        32*128*128
    _Float16* q16 = (_Float16*)(ws + 524288);          // 9,437,184 halves
    _Float16* p16 = q16 + 9437184;
    _Float16* n16 = p16 + 9437184;                     // ends at float 14680064
    float* p1     = ws + 524288;         // 32*32*64*64  (aliases q16, after K1)
    float* p2     = ws + 4718592;        // 32*64*32*32
    float* c3t    = ws + 6815744;        // 32*32*32*128
    float* lossp  = ws + 11010048;       // 32
    float* outp   = (float*)d_out;       // [0..15] pos, [16..31] neg, [32] loss

    hipLaunchKernelGGL(k_cvt16, dim3(4608, 3), dim3(256), 0, stream,
                       anchors, positives, negatives, q16, p16, n16);
    hipLaunchKernelGGL(k_f2f_mfma, dim3(2048), dim3(192), 0, stream,
                       q16, p16, n16, amask, pmask, nmask, simbuf);
    hipLaunchKernelGGL(k_conv1pool, dim3(16, 32), dim3(256), 0, stream,
                       simbuf, w1, b1, p1);
    hipLaunchKernelGGL(k_conv2pool, dim3(8, 32, 32), dim3(256), 0, stream,
                       p1, w2, b2, p2);
    hipLaunchKernelGGL(k_conv3, dim3(2, 32, 32), dim3(256), 0, stream,
                       p2, w3, b3, c3t);
    hipLaunchKernelGGL(k_final, dim3(32), dim3(256), 0, stream,
                       c3t, fw, fbias, amask, pmask, nmask, outp, lossp);
    hipLaunchKernelGGL(k_losssum, dim3(1), dim3(64), 0, stream, lossp, outp);
}

// Round 8
// 298.883 us; speedup vs baseline: 2.9546x; 1.5332x over previous
//
#include <hip/hip_runtime.h>
#include <float.h>
#include <cstdint>

#define BB 16
#define TT 128
#define RG 9
#define DD 512

typedef _Float16 half8 __attribute__((ext_vector_type(8)));
typedef float f32x4 __attribute__((ext_vector_type(4)));

// ---------------------------------------------------------------------------
// K0a: weight re-layout to f16: w2 [64][32][3][3] -> w2h [oc][tap][ic32];
//      w3 [128][64][3][3] -> w3h [oc][tap][ic64].
// ---------------------------------------------------------------------------
__global__ __launch_bounds__(256) void k_wprep(
    const float* __restrict__ w2, const float* __restrict__ w3,
    _Float16* __restrict__ w2h, _Float16* __restrict__ w3h)
{
    const int e = blockIdx.x * 256 + threadIdx.x;
    if (e < 18432) {
        const int oc = e / 288, rem = e - oc * 288;
        const int ic = rem / 9, t = rem - ic * 9;
        w2h[(oc * 9 + t) * 32 + ic] = (_Float16)w2[e];
    } else if (e < 18432 + 73728) {
        const int e2 = e - 18432;
        const int oc = e2 / 576, rem = e2 - oc * 576;
        const int ic = rem / 9, t = rem - ic * 9;
        w3h[(oc * 9 + t) * 64 + ic] = (_Float16)w3[e2];
    }
}

// ---------------------------------------------------------------------------
// K0b: one-time f32 -> f16 (RNE) conversion of the three feature tensors.
// Each tensor: 9,437,184 elements = 4608 blocks x 256 thr x 8 elem.
// ---------------------------------------------------------------------------
__global__ __launch_bounds__(256) void k_cvt16(
    const float* __restrict__ a, const float* __restrict__ p,
    const float* __restrict__ n,
    _Float16* __restrict__ da, _Float16* __restrict__ dp,
    _Float16* __restrict__ dn)
{
    const int which = blockIdx.y;
    const float* __restrict__ s = (which == 0) ? a : (which == 1) ? p : n;
    _Float16* __restrict__ d    = (which == 0) ? da : (which == 1) ? dp : dn;
    const size_t i = (size_t)blockIdx.x * 256 + threadIdx.x;
    const float4 v0 = reinterpret_cast<const float4*>(s)[2 * i];
    const float4 v1 = reinterpret_cast<const float4*>(s)[2 * i + 1];
    half8 h;
    h[0] = (_Float16)v0.x; h[1] = (_Float16)v0.y;
    h[2] = (_Float16)v0.z; h[3] = (_Float16)v0.w;
    h[4] = (_Float16)v1.x; h[5] = (_Float16)v1.y;
    h[6] = (_Float16)v1.z; h[7] = (_Float16)v1.w;
    *reinterpret_cast<half8*>(d + i * 8) = h;
}

// ---------------------------------------------------------------------------
// K1 (MFMA, LDS-free, barrier-free): f2f chamfer similarity from f16 data.
// grid 2048 linear (XCD-bijective swizzle), block 192 (3 waves, o {3,3,3}).
// ---------------------------------------------------------------------------
__global__ __launch_bounds__(192) void k_f2f_mfma(
    const _Float16* __restrict__ q16,
    const _Float16* __restrict__ p16,
    const _Float16* __restrict__ n16,
    const float* __restrict__ amask,
    const float* __restrict__ pmask,
    const float* __restrict__ nmask,
    float* __restrict__ simbuf)
{
    __shared__ float red[768];

    const int tid = threadIdx.x;
    const int lane = tid & 63, wave = tid >> 6;
    const int lo = lane & 15, hi = lane >> 4;

    const int hw = blockIdx.x;
    const int L  = (hw & 7) * 256 + (hw >> 3);
    const int tb = L >> 6;
    const int it = (L >> 3) & 7;
    const int jt = L & 7;

    const int b = tb & 15;
    const _Float16* __restrict__ tptr = (tb < BB) ? p16 : n16;
    const float* __restrict__ tmk  = (tb < BB) ? pmask : nmask;
    const int i0 = it * 16, j0 = jt * 16;

    const _Float16* __restrict__ qrow =
        q16 + (size_t)((b * TT + i0 + lo) * RG) * DD + hi * 8;
    const _Float16* __restrict__ trow =
        tptr + (size_t)((b * TT + j0 + lo) * RG) * DD + hi * 8;

    const int o0 = wave * 3;

    f32x4 acc[3][9];
#pragma unroll
    for (int oi = 0; oi < 3; ++oi)
#pragma unroll
        for (int p = 0; p < 9; ++p)
            acc[oi][p] = (f32x4){0.f, 0.f, 0.f, 0.f};

    for (int kc = 0; kc < DD; kc += 32) {
        const half8 a0 = *reinterpret_cast<const half8*>(qrow + (size_t)(o0 + 0) * DD + kc);
        const half8 a1 = *reinterpret_cast<const half8*>(qrow + (size_t)(o0 + 1) * DD + kc);
        const half8 a2 = *reinterpret_cast<const half8*>(qrow + (size_t)(o0 + 2) * DD + kc);
#pragma unroll
        for (int p = 0; p < 9; ++p) {
            const half8 bf = *reinterpret_cast<const half8*>(trow + (size_t)p * DD + kc);
            acc[0][p] = __builtin_amdgcn_mfma_f32_16x16x32_f16(a0, bf, acc[0][p], 0, 0, 0);
            acc[1][p] = __builtin_amdgcn_mfma_f32_16x16x32_f16(a1, bf, acc[1][p], 0, 0, 0);
            acc[2][p] = __builtin_amdgcn_mfma_f32_16x16x32_f16(a2, bf, acc[2][p], 0, 0, 0);
        }
    }

    f32x4 part = {0.f, 0.f, 0.f, 0.f};
#pragma unroll
    for (int oi = 0; oi < 3; ++oi) {
        f32x4 m = acc[oi][0];
#pragma unroll
        for (int p = 1; p < 9; ++p) {
            m[0] = fmaxf(m[0], acc[oi][p][0]);
            m[1] = fmaxf(m[1], acc[oi][p][1]);
            m[2] = fmaxf(m[2], acc[oi][p][2]);
            m[3] = fmaxf(m[3], acc[oi][p][3]);
        }
        part[0] += m[0]; part[1] += m[1]; part[2] += m[2]; part[3] += m[3];
    }

    *reinterpret_cast<f32x4*>(red + (size_t)(wave * 64 + lane) * 4) = part;
    __syncthreads();
    if (wave == 0) {
        const f32x4 t0 = *reinterpret_cast<const f32x4*>(red + (size_t)lane * 4);
        const f32x4 t1 = *reinterpret_cast<const f32x4*>(red + (size_t)(64 + lane) * 4);
        const f32x4 t2 = *reinterpret_cast<const f32x4*>(red + (size_t)(128 + lane) * 4);
        const int j = j0 + lo;
        const float tm = tmk[b * TT + j];
#pragma unroll
        for (int r = 0; r < 4; ++r) {
            const int i = i0 + hi * 4 + r;
            const float mk = amask[b * TT + i] * tm;
            const float s = (t0[r] + t1[r] + t2[r]) * (1.f / 9.f);
            simbuf[((size_t)tb * TT + i) * TT + j] = (mk > 0.f) ? s : 0.f;
        }
    }
}

// ---------------------------------------------------------------------------
// K2: conv1(1->32) + bias + relu + maxpool2. Output: channel-last f16 PADDED
// p1pad[tb][66][66][32] (border zeroed by memset; interior written here).
// ---------------------------------------------------------------------------
__global__ __launch_bounds__(256) void k_conv1pool(
    const float* __restrict__ simbuf, const float* __restrict__ w1,
    const float* __restrict__ b1, _Float16* __restrict__ p1pad)
{
    __shared__ float wl[288];
    __shared__ float bl[32];
    const int tid = threadIdx.x;
    const int tb = blockIdx.y, yg = blockIdx.x;
    for (int e = tid; e < 288; e += 256) wl[e] = w1[e];
    if (tid < 32)  bl[tid] = b1[tid];
    __syncthreads();

    const int y = yg * 4 + (tid >> 6);
    const int x = tid & 63;
    const float* __restrict__ sp = simbuf + (size_t)tb * TT * TT;

    float iv[4][4];
#pragma unroll
    for (int r = 0; r < 4; ++r) {
        const int gy = 2 * y - 1 + r;
#pragma unroll
        for (int c = 0; c < 4; ++c) {
            const int gx = 2 * x - 1 + c;
            iv[r][c] = (gy >= 0 && gy < TT && gx >= 0 && gx < TT)
                           ? sp[gy * TT + gx] : 0.f;
        }
    }
    _Float16 hv[32];
#pragma unroll
    for (int oc = 0; oc < 32; ++oc) {
        float a00 = 0.f, a01 = 0.f, a10 = 0.f, a11 = 0.f;
#pragma unroll
        for (int rr = 0; rr < 3; ++rr)
#pragma unroll
            for (int cc = 0; cc < 3; ++cc) {
                const float w = wl[oc * 9 + rr * 3 + cc];
                a00 = fmaf(w, iv[rr][cc],         a00);
                a01 = fmaf(w, iv[rr][cc + 1],     a01);
                a10 = fmaf(w, iv[rr + 1][cc],     a10);
                a11 = fmaf(w, iv[rr + 1][cc + 1], a11);
            }
        float m = fmaxf(fmaxf(a00, a01), fmaxf(a10, a11)) + bl[oc];
        hv[oc] = (_Float16)fmaxf(m, 0.f);
    }
    _Float16* dst = p1pad + (((size_t)tb * 66 + 1 + y) * 66 + 1 + x) * 32;
#pragma unroll
    for (int g = 0; g < 4; ++g)
        *reinterpret_cast<half8*>(dst + g * 8) = *reinterpret_cast<const half8*>(hv + g * 8);
}

// ---------------------------------------------------------------------------
// K3 (MFMA): conv2(32->64) + bias + relu + maxpool2, all in-register.
// A-frag = 16 x-pixels (row=lo, k=ic), B-frag = 16 oc weights; C row=x, col=oc.
// Wave: 2 conv rows x 9 taps = 18 MFMA -> 2x2 pool in-lane -> p2pad f16.
// grid (4 xh, 32 Y, 32 tb), 4 waves = 4 oc tiles.
// ---------------------------------------------------------------------------
__global__ __launch_bounds__(256) void k_conv2_mfma(
    const _Float16* __restrict__ p1pad, const _Float16* __restrict__ w2h,
    const float* __restrict__ b2, _Float16* __restrict__ p2pad)
{
    const int tid = threadIdx.x;
    const int lane = tid & 63, wave = tid >> 6;
    const int lo = lane & 15, hi = lane >> 4;
    const int xh = blockIdx.x, Y = blockIdx.y, tb = blockIdx.z;
    const int oc0 = wave * 16;
    const int y0 = 2 * Y;

    half8 wf[9];
    const _Float16* wb = w2h + (size_t)(oc0 + lo) * 288 + hi * 8;
#pragma unroll
    for (int t = 0; t < 9; ++t)
        wf[t] = *reinterpret_cast<const half8*>(wb + t * 32);

    f32x4 acc0 = {0.f, 0.f, 0.f, 0.f};
    f32x4 acc1 = {0.f, 0.f, 0.f, 0.f};
#pragma unroll
    for (int dy = 0; dy < 3; ++dy) {
#pragma unroll
        for (int dx = 0; dx < 3; ++dx) {
            const int col = xh * 16 + dx + lo;
            const half8 a0 = *reinterpret_cast<const half8*>(
                p1pad + (((size_t)tb * 66 + (y0 + dy)) * 66 + col) * 32 + hi * 8);
            const half8 a1 = *reinterpret_cast<const half8*>(
                p1pad + (((size_t)tb * 66 + (y0 + 1 + dy)) * 66 + col) * 32 + hi * 8);
            const half8 w = wf[dy * 3 + dx];
            acc0 = __builtin_amdgcn_mfma_f32_16x16x32_f16(a0, w, acc0, 0, 0, 0);
            acc1 = __builtin_amdgcn_mfma_f32_16x16x32_f16(a1, w, acc1, 0, 0, 0);
        }
    }
    const float bias = b2[oc0 + lo];
    float p0 = fmaxf(fmaxf(acc0[0], acc0[1]), fmaxf(acc1[0], acc1[1]));
    float p1v = fmaxf(fmaxf(acc0[2], acc0[3]), fmaxf(acc1[2], acc1[3]));
    p0  = fmaxf(p0 + bias, 0.f);
    p1v = fmaxf(p1v + bias, 0.f);
    const int xo = xh * 8 + 2 * hi;
    _Float16* dst = p2pad + (((size_t)tb * 34 + 1 + Y) * 34 + 1 + xo) * 64 + oc0 + lo;
    dst[0]  = (_Float16)p0;
    dst[64] = (_Float16)p1v;
}

// ---------------------------------------------------------------------------
// K4 (MFMA): conv3(64->128) + bias + relu -> c3t [tb][y][x][128] f32.
// Wave: 9 taps x 2 k-halves = 18 MFMA into one 16x16 C tile.
// grid (4, 32 y, 32 tb); wave+block.x -> (xh 0..1, oc-tile 0..7).
// ---------------------------------------------------------------------------
__global__ __launch_bounds__(256) void k_conv3_mfma(
    const _Float16* __restrict__ p2pad, const _Float16* __restrict__ w3h,
    const float* __restrict__ b3, float* __restrict__ c3t)
{
    const int tid = threadIdx.x;
    const int lane = tid & 63, wave = tid >> 6;
    const int lo = lane & 15, hi = lane >> 4;
    const int idx = blockIdx.x * 4 + wave;     // 0..15
    const int xh = idx & 1, oct = idx >> 1;
    const int y = blockIdx.y, tb = blockIdx.z;
    const int oc0 = oct * 16;

    half8 wf0[9], wf1[9];
    const _Float16* wb = w3h + (size_t)(oc0 + lo) * 576 + hi * 8;
#pragma unroll
    for (int t = 0; t < 9; ++t) {
        wf0[t] = *reinterpret_cast<const half8*>(wb + t * 64);
        wf1[t] = *reinterpret_cast<const half8*>(wb + t * 64 + 32);
    }

    f32x4 acc = {0.f, 0.f, 0.f, 0.f};
#pragma unroll
    for (int dy = 0; dy < 3; ++dy) {
#pragma unroll
        for (int dx = 0; dx < 3; ++dx) {
            const int col = xh * 16 + dx + lo;
            const size_t base = (((size_t)tb * 34 + (y + dy)) * 34 + col) * 64 + hi * 8;
            const half8 a0 = *reinterpret_cast<const half8*>(p2pad + base);
            const half8 a1 = *reinterpret_cast<const half8*>(p2pad + base + 32);
            acc = __builtin_amdgcn_mfma_f32_16x16x32_f16(a0, wf0[dy * 3 + dx], acc, 0, 0, 0);
            acc = __builtin_amdgcn_mfma_f32_16x16x32_f16(a1, wf1[dy * 3 + dx], acc, 0, 0, 0);
        }
    }
    const float bias = b3[oc0 + lo];
    float* dst = c3t + (((size_t)tb * 32 + y) * 32 + xh * 16 + 4 * hi) * 128 + oc0 + lo;
#pragma unroll
    for (int r = 0; r < 4; ++r)
        dst[(size_t)r * 128] = fmaxf(acc[r] + bias, 0.f);
}

// ---------------------------------------------------------------------------
// K5: fconv (1x1, 128->1) + bias, hinge loss, clip, v2v -> out. 1 block/tb.
// ---------------------------------------------------------------------------
__global__ __launch_bounds__(256) void k_final(
    const float* __restrict__ c3t, const float* __restrict__ fw,
    const float* __restrict__ fb, const float* __restrict__ amask,
    const float* __restrict__ pmask, const float* __restrict__ nmask,
    float* __restrict__ out, float* __restrict__ lossp)
{
    __shared__ __align__(16) float fwl[128];
    __shared__ float qmax4[32], tmax4[32];
    __shared__ float sval[1024];
    __shared__ float red[256];
    __shared__ float rowv[32], rowm[32];
    const int tid = threadIdx.x, tb = blockIdx.x;
    const int b = tb & 15;
    const float* __restrict__ tmk = (tb < BB) ? pmask : nmask;

    if (tid < 128) fwl[tid] = fw[tid];
    if (tid < 32) {
        const float* qp = amask + b * TT + 4 * tid;
        qmax4[tid] = fmaxf(fmaxf(qp[0], qp[1]), fmaxf(qp[2], qp[3]));
        const float* tp = tmk + b * TT + 4 * tid;
        tmax4[tid] = fmaxf(fmaxf(tp[0], tp[1]), fmaxf(tp[2], tp[3]));
    }
    __syncthreads();

    const float fbv = fb[0];
    float lt = 0.f;
    for (int l = 0; l < 4; ++l) {
        const int loc = tid + 256 * l;
        const int y = loc >> 5, x = loc & 31;
        const float* __restrict__ pc = c3t + ((size_t)(tb * 32 + y) * 32 + x) * 128;
        float s = fbv;
        for (int c4 = 0; c4 < 128; c4 += 4) {
            const float4 wv = *reinterpret_cast<const float4*>(&fwl[c4]);
            const float4 cv = *reinterpret_cast<const float4*>(&pc[c4]);
            s += wv.x * cv.x + wv.y * cv.y + wv.z * cv.z + wv.w * cv.w;
        }
        lt += fmaxf(0.f, -1.f - s) + fmaxf(0.f, s - 1.f);
        const float sc = fminf(fmaxf(s, -1.f), 1.f);
        const float m = qmax4[y] * tmax4[x];
        sval[loc] = (m > 0.f) ? sc : -FLT_MAX;
    }
    red[tid] = lt;
    __syncthreads();
    for (int off = 128; off > 0; off >>= 1) {
        if (tid < off) red[tid] += red[tid + off];
        __syncthreads();
    }
    if (tid == 0) lossp[tb] = red[0];

    if (tid < 32) {
        const int y = tid;
        float rm = -FLT_MAX, mm = -FLT_MAX;
        for (int x = 0; x < 32; ++x) {
            const float m = qmax4[y] * tmax4[x];
            mm = fmaxf(mm, m);
            if (m > 0.f) rm = fmaxf(rm, sval[y * 32 + x]);
        }
        rowv[y] = (mm > 0.f) ? rm : 0.f;
        rowm[y] = mm;
    }
    __syncthreads();
    if (tid == 0) {
        float num = 0.f, den = 0.f;
        for (int yy = 0; yy < 32; ++yy) { num += rowv[yy]; den += rowm[yy]; }
        out[tb] = num / den;
    }
}

__global__ void k_losssum(const float* __restrict__ lossp, float* __restrict__ out)
{
    if (threadIdx.x == 0) {
        float s = 0.f;
        for (int i = 0; i < 32; ++i) s += lossp[i];
        out[32] = s;
    }
}

// ---------------------------------------------------------------------------
extern "C" void kernel_launch(void* const* d_in, const int* in_sizes, int n_in,
                              void* d_out, int out_size, void* d_ws, size_t ws_size,
                              hipStream_t stream)
{
    (void)in_sizes; (void)n_in; (void)out_size; (void)ws_size;
    const float* anchors   = (const float*)d_in[0];
    const float* positives = (const float*)d_in[1];
    const float* negatives = (const float*)d_in[2];
    const float* amask     = (const float*)d_in[3];
    const float* pmask     = (const float*)d_in[4];
    const float* nmask     = (const float*)d_in[5];
    const float* w1 = (const float*)d_in[6];
    const float* b1 = (const float*)d_in[7];
    const float* w2 = (const float*)d_in[8];
    const float* b2 = (const float*)d_in[9];
    const float* w3 = (const float*)d_in[10];
    const float* b3 = (const float*)d_in[11];
    const float* fw = (const float*)d_in[12];
    const float* fbias = (const float*)d_in[13];

    // Workspace (float offsets). f16 features [524288, 14680064) die after K1;
    // p1pad/p2pad/c3t reuse that region (stream-ordered). w2h/w3h/lossp live
    // beyond 14680064 (ws >= 72 MB per round-6 run). Peak ~58.9 MB.
    float* ws     = (float*)d_ws;
    float* simbuf = ws;                                    // 524288 f
    _Float16* q16 = (_Float16*)(ws + 524288);              // 9437184 h
    _Float16* p16 = q16 + 9437184;
    _Float16* n16 = p16 + 9437184;                         // ends f 14680064
    _Float16* p1pad = (_Float16*)(ws + 524288);            // 66*66*32*32 h = 4460544
    _Float16* p2pad = (_Float16*)(ws + 2754560);           // 34*34*64*32 h = 2367488
    float* c3t    = ws + 3938304;                          // 4194304 f (ends 8132608)
    _Float16* w2h = (_Float16*)(ws + 14680064);            // 18432 h
    _Float16* w3h = (_Float16*)(ws + 14689280);            // 73728 h
    float* lossp  = ws + 14726144;                         // 32
    float* outp   = (float*)d_out;

    hipLaunchKernelGGL(k_wprep, dim3(360), dim3(256), 0, stream, w2, w3, w2h, w3h);
    hipLaunchKernelGGL(k_cvt16, dim3(4608, 3), dim3(256), 0, stream,
                       anchors, positives, negatives, q16, p16, n16);
    hipLaunchKernelGGL(k_f2f_mfma, dim3(2048), dim3(192), 0, stream,
                       q16, p16, n16, amask, pmask, nmask, simbuf);
    // zero the padded borders (after K1: regions alias the dead f16 features)
    hipMemsetAsync(p1pad, 0, (size_t)4460544 * 2, stream);
    hipMemsetAsync(p2pad, 0, (size_t)2367488 * 2, stream);
    hipLaunchKernelGGL(k_conv1pool, dim3(16, 32), dim3(256), 0, stream,
                       simbuf, w1, b1, p1pad);
    hipLaunchKernelGGL(k_conv2_mfma, dim3(4, 32, 32), dim3(256), 0, stream,
                       p1pad, w2h, b2, p2pad);
    hipLaunchKernelGGL(k_conv3_mfma, dim3(4, 32, 32), dim3(256), 0, stream,
                       p2pad, w3h, b3, c3t);
    hipLaunchKernelGGL(k_final, dim3(32), dim3(256), 0, stream,
                       c3t, fw, fbias, amask, pmask, nmask, outp, lossp);
    hipLaunchKernelGGL(k_losssum, dim3(1), dim3(64), 0, stream, lossp, outp);
}

// Round 9
// 290.932 us; speedup vs baseline: 3.0353x; 1.0273x over previous
//
#include <hip/hip_runtime.h>
#include <float.h>
#include <cstdint>

#define BB 16
#define TT 128
#define RG 9
#define DD 512

typedef _Float16 half8 __attribute__((ext_vector_type(8)));
typedef float f32x4 __attribute__((ext_vector_type(4)));

// ---------------------------------------------------------------------------
// K0a: weight re-layout to f16: w2 [64][32][3][3] -> w2h [oc][tap][ic32];
//      w3 [128][64][3][3] -> w3h [oc][tap][ic64].
// ---------------------------------------------------------------------------
__global__ __launch_bounds__(256) void k_wprep(
    const float* __restrict__ w2, const float* __restrict__ w3,
    _Float16* __restrict__ w2h, _Float16* __restrict__ w3h)
{
    const int e = blockIdx.x * 256 + threadIdx.x;
    if (e < 18432) {
        const int oc = e / 288, rem = e - oc * 288;
        const int ic = rem / 9, t = rem - ic * 9;
        w2h[(oc * 9 + t) * 32 + ic] = (_Float16)w2[e];
    } else if (e < 18432 + 73728) {
        const int e2 = e - 18432;
        const int oc = e2 / 576, rem = e2 - oc * 576;
        const int ic = rem / 9, t = rem - ic * 9;
        w3h[(oc * 9 + t) * 64 + ic] = (_Float16)w3[e2];
    }
}

// ---------------------------------------------------------------------------
// K0b: one-time f32 -> f16 (RNE) conversion of the three feature tensors.
// ---------------------------------------------------------------------------
__global__ __launch_bounds__(256) void k_cvt16(
    const float* __restrict__ a, const float* __restrict__ p,
    const float* __restrict__ n,
    _Float16* __restrict__ da, _Float16* __restrict__ dp,
    _Float16* __restrict__ dn)
{
    const int which = blockIdx.y;
    const float* __restrict__ s = (which == 0) ? a : (which == 1) ? p : n;
    _Float16* __restrict__ d    = (which == 0) ? da : (which == 1) ? dp : dn;
    const size_t i = (size_t)blockIdx.x * 256 + threadIdx.x;
    const float4 v0 = reinterpret_cast<const float4*>(s)[2 * i];
    const float4 v1 = reinterpret_cast<const float4*>(s)[2 * i + 1];
    half8 h;
    h[0] = (_Float16)v0.x; h[1] = (_Float16)v0.y;
    h[2] = (_Float16)v0.z; h[3] = (_Float16)v0.w;
    h[4] = (_Float16)v1.x; h[5] = (_Float16)v1.y;
    h[6] = (_Float16)v1.z; h[7] = (_Float16)v1.w;
    *reinterpret_cast<half8*>(d + i * 8) = h;
}

// ---------------------------------------------------------------------------
// K1 (MFMA, LDS-free, software-pipelined): f2f chamfer similarity.
// Per wave: acc[3 o][9 p]; per 32-k chunk: 12 direct-global 16-B fragment
// loads + 27 MFMA. NEW: 2-deep register double-buffer — chunk k+1's loads
// issue under chunk k's MFMAs (named A/B frag sets, static indexing).
// grid 2048 linear (XCD-bijective swizzle), block 192 (3 waves, o {3,3,3}).
// ---------------------------------------------------------------------------
__global__ __launch_bounds__(192) void k_f2f_mfma(
    const _Float16* __restrict__ q16,
    const _Float16* __restrict__ p16,
    const _Float16* __restrict__ n16,
    const float* __restrict__ amask,
    const float* __restrict__ pmask,
    const float* __restrict__ nmask,
    float* __restrict__ simbuf)
{
    __shared__ float red[768];

    const int tid = threadIdx.x;
    const int lane = tid & 63, wave = tid >> 6;
    const int lo = lane & 15, hi = lane >> 4;

    const int hw = blockIdx.x;
    const int L  = (hw & 7) * 256 + (hw >> 3);
    const int tb = L >> 6;
    const int it = (L >> 3) & 7;
    const int jt = L & 7;

    const int b = tb & 15;
    const _Float16* __restrict__ tptr = (tb < BB) ? p16 : n16;
    const float* __restrict__ tmk  = (tb < BB) ? pmask : nmask;
    const int i0 = it * 16, j0 = jt * 16;

    const _Float16* __restrict__ qrow =
        q16 + (size_t)((b * TT + i0 + lo) * RG) * DD + hi * 8;
    const _Float16* __restrict__ trow =
        tptr + (size_t)((b * TT + j0 + lo) * RG) * DD + hi * 8;

    const int o0 = wave * 3;
    const _Float16* __restrict__ qp0 = qrow + (size_t)(o0 + 0) * DD;
    const _Float16* __restrict__ qp1 = qrow + (size_t)(o0 + 1) * DD;
    const _Float16* __restrict__ qp2 = qrow + (size_t)(o0 + 2) * DD;

    f32x4 acc[3][9];
#pragma unroll
    for (int oi = 0; oi < 3; ++oi)
#pragma unroll
        for (int p = 0; p < 9; ++p)
            acc[oi][p] = (f32x4){0.f, 0.f, 0.f, 0.f};

#define LDQ(d0, d1, d2, kc)                                          \
    d0 = *reinterpret_cast<const half8*>(qp0 + (kc));                \
    d1 = *reinterpret_cast<const half8*>(qp1 + (kc));                \
    d2 = *reinterpret_cast<const half8*>(qp2 + (kc));

#define LDT(dst, kc)                                                 \
    _Pragma("unroll")                                                \
    for (int p = 0; p < 9; ++p)                                      \
        dst[p] = *reinterpret_cast<const half8*>(trow + (size_t)p * DD + (kc));

#define STEP(A0, A1, A2, T)                                          \
    _Pragma("unroll")                                                \
    for (int p = 0; p < 9; ++p) {                                    \
        acc[0][p] = __builtin_amdgcn_mfma_f32_16x16x32_f16(A0, T[p], acc[0][p], 0, 0, 0); \
        acc[1][p] = __builtin_amdgcn_mfma_f32_16x16x32_f16(A1, T[p], acc[1][p], 0, 0, 0); \
        acc[2][p] = __builtin_amdgcn_mfma_f32_16x16x32_f16(A2, T[p], acc[2][p], 0, 0, 0); \
    }

    half8 qa0, qa1, qa2, qb0, qb1, qb2;
    half8 ta[9], tbf[9];

    // prologue: chunk 0 into A
    LDQ(qa0, qa1, qa2, 0)
    LDT(ta, 0)

    // main: 7 iterations of 64 k (chunks 0..13), then tail (14, 15)
    for (int kc = 0; kc < DD - 64; kc += 64) {
        LDQ(qb0, qb1, qb2, kc + 32)
        LDT(tbf, kc + 32)
        STEP(qa0, qa1, qa2, ta)
        LDQ(qa0, qa1, qa2, kc + 64)
        LDT(ta, kc + 64)
        STEP(qb0, qb1, qb2, tbf)
    }
    LDQ(qb0, qb1, qb2, DD - 32)
    LDT(tbf, DD - 32)
    STEP(qa0, qa1, qa2, ta)
    STEP(qb0, qb1, qb2, tbf)

#undef LDQ
#undef LDT
#undef STEP

    f32x4 part = {0.f, 0.f, 0.f, 0.f};
#pragma unroll
    for (int oi = 0; oi < 3; ++oi) {
        f32x4 m = acc[oi][0];
#pragma unroll
        for (int p = 1; p < 9; ++p) {
            m[0] = fmaxf(m[0], acc[oi][p][0]);
            m[1] = fmaxf(m[1], acc[oi][p][1]);
            m[2] = fmaxf(m[2], acc[oi][p][2]);
            m[3] = fmaxf(m[3], acc[oi][p][3]);
        }
        part[0] += m[0]; part[1] += m[1]; part[2] += m[2]; part[3] += m[3];
    }

    *reinterpret_cast<f32x4*>(red + (size_t)(wave * 64 + lane) * 4) = part;
    __syncthreads();
    if (wave == 0) {
        const f32x4 t0 = *reinterpret_cast<const f32x4*>(red + (size_t)lane * 4);
        const f32x4 t1 = *reinterpret_cast<const f32x4*>(red + (size_t)(64 + lane) * 4);
        const f32x4 t2 = *reinterpret_cast<const f32x4*>(red + (size_t)(128 + lane) * 4);
        const int j = j0 + lo;
        const float tm = tmk[b * TT + j];
#pragma unroll
        for (int r = 0; r < 4; ++r) {
            const int i = i0 + hi * 4 + r;
            const float mk = amask[b * TT + i] * tm;
            const float s = (t0[r] + t1[r] + t2[r]) * (1.f / 9.f);
            simbuf[((size_t)tb * TT + i) * TT + j] = (mk > 0.f) ? s : 0.f;
        }
    }
}

// ---------------------------------------------------------------------------
// K2: conv1(1->32) + bias + relu + maxpool2 -> channel-last f16 PADDED
// p1pad[tb][66][66][32].
// ---------------------------------------------------------------------------
__global__ __launch_bounds__(256) void k_conv1pool(
    const float* __restrict__ simbuf, const float* __restrict__ w1,
    const float* __restrict__ b1, _Float16* __restrict__ p1pad)
{
    __shared__ float wl[288];
    __shared__ float bl[32];
    const int tid = threadIdx.x;
    const int tb = blockIdx.y, yg = blockIdx.x;
    for (int e = tid; e < 288; e += 256) wl[e] = w1[e];
    if (tid < 32)  bl[tid] = b1[tid];
    __syncthreads();

    const int y = yg * 4 + (tid >> 6);
    const int x = tid & 63;
    const float* __restrict__ sp = simbuf + (size_t)tb * TT * TT;

    float iv[4][4];
#pragma unroll
    for (int r = 0; r < 4; ++r) {
        const int gy = 2 * y - 1 + r;
#pragma unroll
        for (int c = 0; c < 4; ++c) {
            const int gx = 2 * x - 1 + c;
            iv[r][c] = (gy >= 0 && gy < TT && gx >= 0 && gx < TT)
                           ? sp[gy * TT + gx] : 0.f;
        }
    }
    _Float16 hv[32];
#pragma unroll
    for (int oc = 0; oc < 32; ++oc) {
        float a00 = 0.f, a01 = 0.f, a10 = 0.f, a11 = 0.f;
#pragma unroll
        for (int rr = 0; rr < 3; ++rr)
#pragma unroll
            for (int cc = 0; cc < 3; ++cc) {
                const float w = wl[oc * 9 + rr * 3 + cc];
                a00 = fmaf(w, iv[rr][cc],         a00);
                a01 = fmaf(w, iv[rr][cc + 1],     a01);
                a10 = fmaf(w, iv[rr + 1][cc],     a10);
                a11 = fmaf(w, iv[rr + 1][cc + 1], a11);
            }
        float m = fmaxf(fmaxf(a00, a01), fmaxf(a10, a11)) + bl[oc];
        hv[oc] = (_Float16)fmaxf(m, 0.f);
    }
    _Float16* dst = p1pad + (((size_t)tb * 66 + 1 + y) * 66 + 1 + x) * 32;
#pragma unroll
    for (int g = 0; g < 4; ++g)
        *reinterpret_cast<half8*>(dst + g * 8) = *reinterpret_cast<const half8*>(hv + g * 8);
}

// ---------------------------------------------------------------------------
// K3 (MFMA): conv2(32->64) + bias + relu + maxpool2 -> p2pad f16.
// ---------------------------------------------------------------------------
__global__ __launch_bounds__(256) void k_conv2_mfma(
    const _Float16* __restrict__ p1pad, const _Float16* __restrict__ w2h,
    const float* __restrict__ b2, _Float16* __restrict__ p2pad)
{
    const int tid = threadIdx.x;
    const int lane = tid & 63, wave = tid >> 6;
    const int lo = lane & 15, hi = lane >> 4;
    const int xh = blockIdx.x, Y = blockIdx.y, tb = blockIdx.z;
    const int oc0 = wave * 16;
    const int y0 = 2 * Y;

    half8 wf[9];
    const _Float16* wb = w2h + (size_t)(oc0 + lo) * 288 + hi * 8;
#pragma unroll
    for (int t = 0; t < 9; ++t)
        wf[t] = *reinterpret_cast<const half8*>(wb + t * 32);

    f32x4 acc0 = {0.f, 0.f, 0.f, 0.f};
    f32x4 acc1 = {0.f, 0.f, 0.f, 0.f};
#pragma unroll
    for (int dy = 0; dy < 3; ++dy) {
#pragma unroll
        for (int dx = 0; dx < 3; ++dx) {
            const int col = xh * 16 + dx + lo;
            const half8 a0 = *reinterpret_cast<const half8*>(
                p1pad + (((size_t)tb * 66 + (y0 + dy)) * 66 + col) * 32 + hi * 8);
            const half8 a1 = *reinterpret_cast<const half8*>(
                p1pad + (((size_t)tb * 66 + (y0 + 1 + dy)) * 66 + col) * 32 + hi * 8);
            const half8 w = wf[dy * 3 + dx];
            acc0 = __builtin_amdgcn_mfma_f32_16x16x32_f16(a0, w, acc0, 0, 0, 0);
            acc1 = __builtin_amdgcn_mfma_f32_16x16x32_f16(a1, w, acc1, 0, 0, 0);
        }
    }
    const float bias = b2[oc0 + lo];
    float p0 = fmaxf(fmaxf(acc0[0], acc0[1]), fmaxf(acc1[0], acc1[1]));
    float p1v = fmaxf(fmaxf(acc0[2], acc0[3]), fmaxf(acc1[2], acc1[3]));
    p0  = fmaxf(p0 + bias, 0.f);
    p1v = fmaxf(p1v + bias, 0.f);
    const int xo = xh * 8 + 2 * hi;
    _Float16* dst = p2pad + (((size_t)tb * 34 + 1 + Y) * 34 + 1 + xo) * 64 + oc0 + lo;
    dst[0]  = (_Float16)p0;
    dst[64] = (_Float16)p1v;
}

// ---------------------------------------------------------------------------
// K4 (MFMA): conv3(64->128) + bias + relu -> c3t [tb][y][x][128] f32.
// ---------------------------------------------------------------------------
__global__ __launch_bounds__(256) void k_conv3_mfma(
    const _Float16* __restrict__ p2pad, const _Float16* __restrict__ w3h,
    const float* __restrict__ b3, float* __restrict__ c3t)
{
    const int tid = threadIdx.x;
    const int lane = tid & 63, wave = tid >> 6;
    const int lo = lane & 15, hi = lane >> 4;
    const int idx = blockIdx.x * 4 + wave;     // 0..15
    const int xh = idx & 1, oct = idx >> 1;
    const int y = blockIdx.y, tb = blockIdx.z;
    const int oc0 = oct * 16;

    half8 wf0[9], wf1[9];
    const _Float16* wb = w3h + (size_t)(oc0 + lo) * 576 + hi * 8;
#pragma unroll
    for (int t = 0; t < 9; ++t) {
        wf0[t] = *reinterpret_cast<const half8*>(wb + t * 64);
        wf1[t] = *reinterpret_cast<const half8*>(wb + t * 64 + 32);
    }

    f32x4 acc = {0.f, 0.f, 0.f, 0.f};
#pragma unroll
    for (int dy = 0; dy < 3; ++dy) {
#pragma unroll
        for (int dx = 0; dx < 3; ++dx) {
            const int col = xh * 16 + dx + lo;
            const size_t base = (((size_t)tb * 34 + (y + dy)) * 34 + col) * 64 + hi * 8;
            const half8 a0 = *reinterpret_cast<const half8*>(p2pad + base);
            const half8 a1 = *reinterpret_cast<const half8*>(p2pad + base + 32);
            acc = __builtin_amdgcn_mfma_f32_16x16x32_f16(a0, wf0[dy * 3 + dx], acc, 0, 0, 0);
            acc = __builtin_amdgcn_mfma_f32_16x16x32_f16(a1, wf1[dy * 3 + dx], acc, 0, 0, 0);
        }
    }
    const float bias = b3[oc0 + lo];
    float* dst = c3t + (((size_t)tb * 32 + y) * 32 + xh * 16 + 4 * hi) * 128 + oc0 + lo;
#pragma unroll
    for (int r = 0; r < 4; ++r)
        dst[(size_t)r * 128] = fmaxf(acc[r] + bias, 0.f);
}

// ---------------------------------------------------------------------------
// K5: fconv (1x1, 128->1) + bias, hinge loss, clip, v2v -> out. 1 block/tb.
// ---------------------------------------------------------------------------
__global__ __launch_bounds__(256) void k_final(
    const float* __restrict__ c3t, const float* __restrict__ fw,
    const float* __restrict__ fb, const float* __restrict__ amask,
    const float* __restrict__ pmask, const float* __restrict__ nmask,
    float* __restrict__ out, float* __restrict__ lossp)
{
    __shared__ __align__(16) float fwl[128];
    __shared__ float qmax4[32], tmax4[32];
    __shared__ float sval[1024];
    __shared__ float red[256];
    __shared__ float rowv[32], rowm[32];
    const int tid = threadIdx.x, tb = blockIdx.x;
    const int b = tb & 15;
    const float* __restrict__ tmk = (tb < BB) ? pmask : nmask;

    if (tid < 128) fwl[tid] = fw[tid];
    if (tid < 32) {
        const float* qp = amask + b * TT + 4 * tid;
        qmax4[tid] = fmaxf(fmaxf(qp[0], qp[1]), fmaxf(qp[2], qp[3]));
        const float* tp = tmk + b * TT + 4 * tid;
        tmax4[tid] = fmaxf(fmaxf(tp[0], tp[1]), fmaxf(tp[2], tp[3]));
    }
    __syncthreads();

    const float fbv = fb[0];
    float lt = 0.f;
    for (int l = 0; l < 4; ++l) {
        const int loc = tid + 256 * l;
        const int y = loc >> 5, x = loc & 31;
        const float* __restrict__ pc = c3t + ((size_t)(tb * 32 + y) * 32 + x) * 128;
        float s = fbv;
        for (int c4 = 0; c4 < 128; c4 += 4) {
            const float4 wv = *reinterpret_cast<const float4*>(&fwl[c4]);
            const float4 cv = *reinterpret_cast<const float4*>(&pc[c4]);
            s += wv.x * cv.x + wv.y * cv.y + wv.z * cv.z + wv.w * cv.w;
        }
        lt += fmaxf(0.f, -1.f - s) + fmaxf(0.f, s - 1.f);
        const float sc = fminf(fmaxf(s, -1.f), 1.f);
        const float m = qmax4[y] * tmax4[x];
        sval[loc] = (m > 0.f) ? sc : -FLT_MAX;
    }
    red[tid] = lt;
    __syncthreads();
    for (int off = 128; off > 0; off >>= 1) {
        if (tid < off) red[tid] += red[tid + off];
        __syncthreads();
    }
    if (tid == 0) lossp[tb] = red[0];

    if (tid < 32) {
        const int y = tid;
        float rm = -FLT_MAX, mm = -FLT_MAX;
        for (int x = 0; x < 32; ++x) {
            const float m = qmax4[y] * tmax4[x];
            mm = fmaxf(mm, m);
            if (m > 0.f) rm = fmaxf(rm, sval[y * 32 + x]);
        }
        rowv[y] = (mm > 0.f) ? rm : 0.f;
        rowm[y] = mm;
    }
    __syncthreads();
    if (tid == 0) {
        float num = 0.f, den = 0.f;
        for (int yy = 0; yy < 32; ++yy) { num += rowv[yy]; den += rowm[yy]; }
        out[tb] = num / den;
    }
}

__global__ void k_losssum(const float* __restrict__ lossp, float* __restrict__ out)
{
    if (threadIdx.x == 0) {
        float s = 0.f;
        for (int i = 0; i < 32; ++i) s += lossp[i];
        out[32] = s;
    }
}

// ---------------------------------------------------------------------------
extern "C" void kernel_launch(void* const* d_in, const int* in_sizes, int n_in,
                              void* d_out, int out_size, void* d_ws, size_t ws_size,
                              hipStream_t stream)
{
    (void)in_sizes; (void)n_in; (void)out_size; (void)ws_size;
    const float* anchors   = (const float*)d_in[0];
    const float* positives = (const float*)d_in[1];
    const float* negatives = (const float*)d_in[2];
    const float* amask     = (const float*)d_in[3];
    const float* pmask     = (const float*)d_in[4];
    const float* nmask     = (const float*)d_in[5];
    const float* w1 = (const float*)d_in[6];
    const float* b1 = (const float*)d_in[7];
    const float* w2 = (const float*)d_in[8];
    const float* b2 = (const float*)d_in[9];
    const float* w3 = (const float*)d_in[10];
    const float* b3 = (const float*)d_in[11];
    const float* fw = (const float*)d_in[12];
    const float* fbias = (const float*)d_in[13];

    // Workspace (float offsets). f16 features [524288, 14680064) die after K1;
    // p1pad/p2pad/c3t reuse that region (stream-ordered). Peak ~58.9 MB.
    float* ws     = (float*)d_ws;
    float* simbuf = ws;                                    // 524288 f
    _Float16* q16 = (_Float16*)(ws + 524288);              // 9437184 h
    _Float16* p16 = q16 + 9437184;
    _Float16* n16 = p16 + 9437184;                         // ends f 14680064
    _Float16* p1pad = (_Float16*)(ws + 524288);            // 66*66*32*32 h
    _Float16* p2pad = (_Float16*)(ws + 2754560);           // 34*34*64*32 h
    float* c3t    = ws + 3938304;                          // 4194304 f
    _Float16* w2h = (_Float16*)(ws + 14680064);            // 18432 h
    _Float16* w3h = (_Float16*)(ws + 14689280);            // 73728 h
    float* lossp  = ws + 14726144;                         // 32
    float* outp   = (float*)d_out;

    hipLaunchKernelGGL(k_wprep, dim3(360), dim3(256), 0, stream, w2, w3, w2h, w3h);
    hipLaunchKernelGGL(k_cvt16, dim3(4608, 3), dim3(256), 0, stream,
                       anchors, positives, negatives, q16, p16, n16);
    hipLaunchKernelGGL(k_f2f_mfma, dim3(2048), dim3(192), 0, stream,
                       q16, p16, n16, amask, pmask, nmask, simbuf);
    hipMemsetAsync(p1pad, 0, (size_t)4460544 * 2, stream);
    hipMemsetAsync(p2pad, 0, (size_t)2367488 * 2, stream);
    hipLaunchKernelGGL(k_conv1pool, dim3(16, 32), dim3(256), 0, stream,
                       simbuf, w1, b1, p1pad);
    hipLaunchKernelGGL(k_conv2_mfma, dim3(4, 32, 32), dim3(256), 0, stream,
                       p1pad, w2h, b2, p2pad);
    hipLaunchKernelGGL(k_conv3_mfma, dim3(4, 32, 32), dim3(256), 0, stream,
                       p2pad, w3h, b3, c3t);
    hipLaunchKernelGGL(k_final, dim3(32), dim3(256), 0, stream,
                       c3t, fw, fbias, amask, pmask, nmask, outp, lossp);
    hipLaunchKernelGGL(k_losssum, dim3(1), dim3(64), 0, stream, lossp, outp);
}

// Round 10
// 250.764 us; speedup vs baseline: 3.5215x; 1.1602x over previous
//
#include <hip/hip_runtime.h>
#include <float.h>
#include <cstdint>

#define BB 16
#define TT 128
#define RG 9
#define DD 512

typedef _Float16 half8 __attribute__((ext_vector_type(8)));
typedef float f32x4 __attribute__((ext_vector_type(4)));

// ---------------------------------------------------------------------------
// K0a: weight re-layout to f16: w2 [64][32][3][3] -> w2h [oc][tap][ic32];
//      w3 [128][64][3][3] -> w3h [oc][tap][ic64].
// ---------------------------------------------------------------------------
__global__ __launch_bounds__(256) void k_wprep(
    const float* __restrict__ w2, const float* __restrict__ w3,
    _Float16* __restrict__ w2h, _Float16* __restrict__ w3h)
{
    const int e = blockIdx.x * 256 + threadIdx.x;
    if (e < 18432) {
        const int oc = e / 288, rem = e - oc * 288;
        const int ic = rem / 9, t = rem - ic * 9;
        w2h[(oc * 9 + t) * 32 + ic] = (_Float16)w2[e];
    } else if (e < 18432 + 73728) {
        const int e2 = e - 18432;
        const int oc = e2 / 576, rem = e2 - oc * 576;
        const int ic = rem / 9, t = rem - ic * 9;
        w3h[(oc * 9 + t) * 64 + ic] = (_Float16)w3[e2];
    }
}

// ---------------------------------------------------------------------------
// K0b (k_pack): f32 -> f16 AND repack into MFMA-fragment order:
//   out[b][tile8][region9][kchunk16][lane64][8halves]   (1 KB per fragment)
// Fragment (b,tl,o,kc): lane = hi*16+lo holds row (tl*16+lo), k = kc*32+hi*8.
// One wave packs one fragment: reads 16 rows x 128 B (full lines), writes
// one contiguous 1 KB burst. Per tensor: 18432 fragments = 4608 blocks x 4 w.
// ---------------------------------------------------------------------------
__global__ __launch_bounds__(256) void k_pack(
    const float* __restrict__ a, const float* __restrict__ p,
    const float* __restrict__ n,
    _Float16* __restrict__ da, _Float16* __restrict__ dp,
    _Float16* __restrict__ dn)
{
    const int which = blockIdx.y;
    const float* __restrict__ s = (which == 0) ? a : (which == 1) ? p : n;
    _Float16* __restrict__ d    = (which == 0) ? da : (which == 1) ? dp : dn;
    const int tid = threadIdx.x;
    const int lane = tid & 63, wave = tid >> 6;
    const int f = blockIdx.x * 4 + wave;          // fragment id, 0..18431
    const int kc = f & 15;
    const int o  = (f >> 4) % 9;
    const int tl = (f / 144) & 7;
    const int b  = f / 1152;
    const int lo = lane & 15, hi = lane >> 4;
    const int row = tl * 16 + lo;
    const float* g = s + ((size_t)((b * TT + row) * RG + o)) * DD + kc * 32 + hi * 8;
    const float4 v0 = *reinterpret_cast<const float4*>(g);
    const float4 v1 = *reinterpret_cast<const float4*>(g + 4);
    half8 h;
    h[0] = (_Float16)v0.x; h[1] = (_Float16)v0.y;
    h[2] = (_Float16)v0.z; h[3] = (_Float16)v0.w;
    h[4] = (_Float16)v1.x; h[5] = (_Float16)v1.y;
    h[6] = (_Float16)v1.z; h[7] = (_Float16)v1.w;
    *reinterpret_cast<half8*>(d + (size_t)f * 512 + lane * 8) = h;
}

// ---------------------------------------------------------------------------
// K1 (MFMA, fragment-packed, software-pipelined): f2f chamfer similarity.
// All fragment loads are base + lane*16B -> fully coalesced 1 KB bursts.
// Strides (halves): kchunk 512, region 8192, tile 73728, b 589824.
// grid 2048 linear (XCD-bijective swizzle), block 192 (3 waves, o {3,3,3}).
// ---------------------------------------------------------------------------
__global__ __launch_bounds__(192) void k_f2f_mfma(
    const _Float16* __restrict__ q16,
    const _Float16* __restrict__ p16,
    const _Float16* __restrict__ n16,
    const float* __restrict__ amask,
    const float* __restrict__ pmask,
    const float* __restrict__ nmask,
    float* __restrict__ simbuf)
{
    __shared__ float red[768];

    const int tid = threadIdx.x;
    const int lane = tid & 63, wave = tid >> 6;
    const int lo = lane & 15, hi = lane >> 4;

    const int hw = blockIdx.x;
    const int L  = (hw & 7) * 256 + (hw >> 3);
    const int tb = L >> 6;
    const int it = (L >> 3) & 7;
    const int jt = L & 7;

    const int b = tb & 15;
    const _Float16* __restrict__ tptr = (tb < BB) ? p16 : n16;
    const float* __restrict__ tmk  = (tb < BB) ? pmask : nmask;
    const int i0 = it * 16, j0 = jt * 16;

    const _Float16* __restrict__ qtile = q16  + (size_t)(b * 8 + it) * 73728 + lane * 8;
    const _Float16* __restrict__ ttile = tptr + (size_t)(b * 8 + jt) * 73728 + lane * 8;

    const int o0 = wave * 3;
    const _Float16* __restrict__ qp0 = qtile + (size_t)(o0 + 0) * 8192;
    const _Float16* __restrict__ qp1 = qtile + (size_t)(o0 + 1) * 8192;
    const _Float16* __restrict__ qp2 = qtile + (size_t)(o0 + 2) * 8192;

    f32x4 acc[3][9];
#pragma unroll
    for (int oi = 0; oi < 3; ++oi)
#pragma unroll
        for (int p = 0; p < 9; ++p)
            acc[oi][p] = (f32x4){0.f, 0.f, 0.f, 0.f};

#define LDQ(d0, d1, d2, ci)                                          \
    d0 = *reinterpret_cast<const half8*>(qp0 + (ci) * 512);          \
    d1 = *reinterpret_cast<const half8*>(qp1 + (ci) * 512);          \
    d2 = *reinterpret_cast<const half8*>(qp2 + (ci) * 512);

#define LDT(dst, ci)                                                 \
    _Pragma("unroll")                                                \
    for (int p = 0; p < 9; ++p)                                      \
        dst[p] = *reinterpret_cast<const half8*>(ttile + (size_t)p * 8192 + (ci) * 512);

#define STEP(A0, A1, A2, T)                                          \
    _Pragma("unroll")                                                \
    for (int p = 0; p < 9; ++p) {                                    \
        acc[0][p] = __builtin_amdgcn_mfma_f32_16x16x32_f16(A0, T[p], acc[0][p], 0, 0, 0); \
        acc[1][p] = __builtin_amdgcn_mfma_f32_16x16x32_f16(A1, T[p], acc[1][p], 0, 0, 0); \
        acc[2][p] = __builtin_amdgcn_mfma_f32_16x16x32_f16(A2, T[p], acc[2][p], 0, 0, 0); \
    }

    half8 qa0, qa1, qa2, qb0, qb1, qb2;
    half8 ta[9], tbf[9];

    // prologue: chunk 0 into A
    LDQ(qa0, qa1, qa2, 0)
    LDT(ta, 0)

    // main: chunk indices 0..13 in the loop, tail handles 14,15
    for (int ci = 0; ci < 14; ci += 2) {
        LDQ(qb0, qb1, qb2, ci + 1)
        LDT(tbf, ci + 1)
        STEP(qa0, qa1, qa2, ta)
        LDQ(qa0, qa1, qa2, ci + 2)
        LDT(ta, ci + 2)
        STEP(qb0, qb1, qb2, tbf)
    }
    LDQ(qb0, qb1, qb2, 15)
    LDT(tbf, 15)
    STEP(qa0, qa1, qa2, ta)
    STEP(qb0, qb1, qb2, tbf)

#undef LDQ
#undef LDT
#undef STEP

    f32x4 part = {0.f, 0.f, 0.f, 0.f};
#pragma unroll
    for (int oi = 0; oi < 3; ++oi) {
        f32x4 m = acc[oi][0];
#pragma unroll
        for (int p = 1; p < 9; ++p) {
            m[0] = fmaxf(m[0], acc[oi][p][0]);
            m[1] = fmaxf(m[1], acc[oi][p][1]);
            m[2] = fmaxf(m[2], acc[oi][p][2]);
            m[3] = fmaxf(m[3], acc[oi][p][3]);
        }
        part[0] += m[0]; part[1] += m[1]; part[2] += m[2]; part[3] += m[3];
    }

    *reinterpret_cast<f32x4*>(red + (size_t)(wave * 64 + lane) * 4) = part;
    __syncthreads();
    if (wave == 0) {
        const f32x4 t0 = *reinterpret_cast<const f32x4*>(red + (size_t)lane * 4);
        const f32x4 t1 = *reinterpret_cast<const f32x4*>(red + (size_t)(64 + lane) * 4);
        const f32x4 t2 = *reinterpret_cast<const f32x4*>(red + (size_t)(128 + lane) * 4);
        const int j = j0 + lo;
        const float tm = tmk[b * TT + j];
#pragma unroll
        for (int r = 0; r < 4; ++r) {
            const int i = i0 + hi * 4 + r;
            const float mk = amask[b * TT + i] * tm;
            const float s = (t0[r] + t1[r] + t2[r]) * (1.f / 9.f);
            simbuf[((size_t)tb * TT + i) * TT + j] = (mk > 0.f) ? s : 0.f;
        }
    }
}

// ---------------------------------------------------------------------------
// K2: conv1(1->32) + bias + relu + maxpool2 -> channel-last f16 PADDED
// p1pad[tb][66][66][32].
// ---------------------------------------------------------------------------
__global__ __launch_bounds__(256) void k_conv1pool(
    const float* __restrict__ simbuf, const float* __restrict__ w1,
    const float* __restrict__ b1, _Float16* __restrict__ p1pad)
{
    __shared__ float wl[288];
    __shared__ float bl[32];
    const int tid = threadIdx.x;
    const int tb = blockIdx.y, yg = blockIdx.x;
    for (int e = tid; e < 288; e += 256) wl[e] = w1[e];
    if (tid < 32)  bl[tid] = b1[tid];
    __syncthreads();

    const int y = yg * 4 + (tid >> 6);
    const int x = tid & 63;
    const float* __restrict__ sp = simbuf + (size_t)tb * TT * TT;

    float iv[4][4];
#pragma unroll
    for (int r = 0; r < 4; ++r) {
        const int gy = 2 * y - 1 + r;
#pragma unroll
        for (int c = 0; c < 4; ++c) {
            const int gx = 2 * x - 1 + c;
            iv[r][c] = (gy >= 0 && gy < TT && gx >= 0 && gx < TT)
                           ? sp[gy * TT + gx] : 0.f;
        }
    }
    _Float16 hv[32];
#pragma unroll
    for (int oc = 0; oc < 32; ++oc) {
        float a00 = 0.f, a01 = 0.f, a10 = 0.f, a11 = 0.f;
#pragma unroll
        for (int rr = 0; rr < 3; ++rr)
#pragma unroll
            for (int cc = 0; cc < 3; ++cc) {
                const float w = wl[oc * 9 + rr * 3 + cc];
                a00 = fmaf(w, iv[rr][cc],         a00);
                a01 = fmaf(w, iv[rr][cc + 1],     a01);
                a10 = fmaf(w, iv[rr + 1][cc],     a10);
                a11 = fmaf(w, iv[rr + 1][cc + 1], a11);
            }
        float m = fmaxf(fmaxf(a00, a01), fmaxf(a10, a11)) + bl[oc];
        hv[oc] = (_Float16)fmaxf(m, 0.f);
    }
    _Float16* dst = p1pad + (((size_t)tb * 66 + 1 + y) * 66 + 1 + x) * 32;
#pragma unroll
    for (int g = 0; g < 4; ++g)
        *reinterpret_cast<half8*>(dst + g * 8) = *reinterpret_cast<const half8*>(hv + g * 8);
}

// ---------------------------------------------------------------------------
// K3 (MFMA): conv2(32->64) + bias + relu + maxpool2 -> p2pad f16.
// ---------------------------------------------------------------------------
__global__ __launch_bounds__(256) void k_conv2_mfma(
    const _Float16* __restrict__ p1pad, const _Float16* __restrict__ w2h,
    const float* __restrict__ b2, _Float16* __restrict__ p2pad)
{
    const int tid = threadIdx.x;
    const int lane = tid & 63, wave = tid >> 6;
    const int lo = lane & 15, hi = lane >> 4;
    const int xh = blockIdx.x, Y = blockIdx.y, tb = blockIdx.z;
    const int oc0 = wave * 16;
    const int y0 = 2 * Y;

    half8 wf[9];
    const _Float16* wb = w2h + (size_t)(oc0 + lo) * 288 + hi * 8;
#pragma unroll
    for (int t = 0; t < 9; ++t)
        wf[t] = *reinterpret_cast<const half8*>(wb + t * 32);

    f32x4 acc0 = {0.f, 0.f, 0.f, 0.f};
    f32x4 acc1 = {0.f, 0.f, 0.f, 0.f};
#pragma unroll
    for (int dy = 0; dy < 3; ++dy) {
#pragma unroll
        for (int dx = 0; dx < 3; ++dx) {
            const int col = xh * 16 + dx + lo;
            const half8 a0 = *reinterpret_cast<const half8*>(
                p1pad + (((size_t)tb * 66 + (y0 + dy)) * 66 + col) * 32 + hi * 8);
            const half8 a1 = *reinterpret_cast<const half8*>(
                p1pad + (((size_t)tb * 66 + (y0 + 1 + dy)) * 66 + col) * 32 + hi * 8);
            const half8 w = wf[dy * 3 + dx];
            acc0 = __builtin_amdgcn_mfma_f32_16x16x32_f16(a0, w, acc0, 0, 0, 0);
            acc1 = __builtin_amdgcn_mfma_f32_16x16x32_f16(a1, w, acc1, 0, 0, 0);
        }
    }
    const float bias = b2[oc0 + lo];
    float p0 = fmaxf(fmaxf(acc0[0], acc0[1]), fmaxf(acc1[0], acc1[1]));
    float p1v = fmaxf(fmaxf(acc0[2], acc0[3]), fmaxf(acc1[2], acc1[3]));
    p0  = fmaxf(p0 + bias, 0.f);
    p1v = fmaxf(p1v + bias, 0.f);
    const int xo = xh * 8 + 2 * hi;
    _Float16* dst = p2pad + (((size_t)tb * 34 + 1 + Y) * 34 + 1 + xo) * 64 + oc0 + lo;
    dst[0]  = (_Float16)p0;
    dst[64] = (_Float16)p1v;
}

// ---------------------------------------------------------------------------
// K4 (MFMA): conv3(64->128) + bias + relu -> c3t [tb][y][x][128] f32.
// ---------------------------------------------------------------------------
__global__ __launch_bounds__(256) void k_conv3_mfma(
    const _Float16* __restrict__ p2pad, const _Float16* __restrict__ w3h,
    const float* __restrict__ b3, float* __restrict__ c3t)
{
    const int tid = threadIdx.x;
    const int lane = tid & 63, wave = tid >> 6;
    const int lo = lane & 15, hi = lane >> 4;
    const int idx = blockIdx.x * 4 + wave;     // 0..15
    const int xh = idx & 1, oct = idx >> 1;
    const int y = blockIdx.y, tb = blockIdx.z;
    const int oc0 = oct * 16;

    half8 wf0[9], wf1[9];
    const _Float16* wb = w3h + (size_t)(oc0 + lo) * 576 + hi * 8;
#pragma unroll
    for (int t = 0; t < 9; ++t) {
        wf0[t] = *reinterpret_cast<const half8*>(wb + t * 64);
        wf1[t] = *reinterpret_cast<const half8*>(wb + t * 64 + 32);
    }

    f32x4 acc = {0.f, 0.f, 0.f, 0.f};
#pragma unroll
    for (int dy = 0; dy < 3; ++dy) {
#pragma unroll
        for (int dx = 0; dx < 3; ++dx) {
            const int col = xh * 16 + dx + lo;
            const size_t base = (((size_t)tb * 34 + (y + dy)) * 34 + col) * 64 + hi * 8;
            const half8 a0 = *reinterpret_cast<const half8*>(p2pad + base);
            const half8 a1 = *reinterpret_cast<const half8*>(p2pad + base + 32);
            acc = __builtin_amdgcn_mfma_f32_16x16x32_f16(a0, wf0[dy * 3 + dx], acc, 0, 0, 0);
            acc = __builtin_amdgcn_mfma_f32_16x16x32_f16(a1, wf1[dy * 3 + dx], acc, 0, 0, 0);
        }
    }
    const float bias = b3[oc0 + lo];
    float* dst = c3t + (((size_t)tb * 32 + y) * 32 + xh * 16 + 4 * hi) * 128 + oc0 + lo;
#pragma unroll
    for (int r = 0; r < 4; ++r)
        dst[(size_t)r * 128] = fmaxf(acc[r] + bias, 0.f);
}

// ---------------------------------------------------------------------------
// K5: fconv (1x1, 128->1) + bias, hinge loss, clip, v2v -> out. 1 block/tb.
// ---------------------------------------------------------------------------
__global__ __launch_bounds__(256) void k_final(
    const float* __restrict__ c3t, const float* __restrict__ fw,
    const float* __restrict__ fb, const float* __restrict__ amask,
    const float* __restrict__ pmask, const float* __restrict__ nmask,
    float* __restrict__ out, float* __restrict__ lossp)
{
    __shared__ __align__(16) float fwl[128];
    __shared__ float qmax4[32], tmax4[32];
    __shared__ float sval[1024];
    __shared__ float red[256];
    __shared__ float rowv[32], rowm[32];
    const int tid = threadIdx.x, tb = blockIdx.x;
    const int b = tb & 15;
    const float* __restrict__ tmk = (tb < BB) ? pmask : nmask;

    if (tid < 128) fwl[tid] = fw[tid];
    if (tid < 32) {
        const float* qp = amask + b * TT + 4 * tid;
        qmax4[tid] = fmaxf(fmaxf(qp[0], qp[1]), fmaxf(qp[2], qp[3]));
        const float* tp = tmk + b * TT + 4 * tid;
        tmax4[tid] = fmaxf(fmaxf(tp[0], tp[1]), fmaxf(tp[2], tp[3]));
    }
    __syncthreads();

    const float fbv = fb[0];
    float lt = 0.f;
    for (int l = 0; l < 4; ++l) {
        const int loc = tid + 256 * l;
        const int y = loc >> 5, x = loc & 31;
        const float* __restrict__ pc = c3t + ((size_t)(tb * 32 + y) * 32 + x) * 128;
        float s = fbv;
        for (int c4 = 0; c4 < 128; c4 += 4) {
            const float4 wv = *reinterpret_cast<const float4*>(&fwl[c4]);
            const float4 cv = *reinterpret_cast<const float4*>(&pc[c4]);
            s += wv.x * cv.x + wv.y * cv.y + wv.z * cv.z + wv.w * cv.w;
        }
        lt += fmaxf(0.f, -1.f - s) + fmaxf(0.f, s - 1.f);
        const float sc = fminf(fmaxf(s, -1.f), 1.f);
        const float m = qmax4[y] * tmax4[x];
        sval[loc] = (m > 0.f) ? sc : -FLT_MAX;
    }
    red[tid] = lt;
    __syncthreads();
    for (int off = 128; off > 0; off >>= 1) {
        if (tid < off) red[tid] += red[tid + off];
        __syncthreads();
    }
    if (tid == 0) lossp[tb] = red[0];

    if (tid < 32) {
        const int y = tid;
        float rm = -FLT_MAX, mm = -FLT_MAX;
        for (int x = 0; x < 32; ++x) {
            const float m = qmax4[y] * tmax4[x];
            mm = fmaxf(mm, m);
            if (m > 0.f) rm = fmaxf(rm, sval[y * 32 + x]);
        }
        rowv[y] = (mm > 0.f) ? rm : 0.f;
        rowm[y] = mm;
    }
    __syncthreads();
    if (tid == 0) {
        float num = 0.f, den = 0.f;
        for (int yy = 0; yy < 32; ++yy) { num += rowv[yy]; den += rowm[yy]; }
        out[tb] = num / den;
    }
}

__global__ void k_losssum(const float* __restrict__ lossp, float* __restrict__ out)
{
    if (threadIdx.x == 0) {
        float s = 0.f;
        for (int i = 0; i < 32; ++i) s += lossp[i];
        out[32] = s;
    }
}

// ---------------------------------------------------------------------------
extern "C" void kernel_launch(void* const* d_in, const int* in_sizes, int n_in,
                              void* d_out, int out_size, void* d_ws, size_t ws_size,
                              hipStream_t stream)
{
    (void)in_sizes; (void)n_in; (void)out_size; (void)ws_size;
    const float* anchors   = (const float*)d_in[0];
    const float* positives = (const float*)d_in[1];
    const float* negatives = (const float*)d_in[2];
    const float* amask     = (const float*)d_in[3];
    const float* pmask     = (const float*)d_in[4];
    const float* nmask     = (const float*)d_in[5];
    const float* w1 = (const float*)d_in[6];
    const float* b1 = (const float*)d_in[7];
    const float* w2 = (const float*)d_in[8];
    const float* b2 = (const float*)d_in[9];
    const float* w3 = (const float*)d_in[10];
    const float* b3 = (const float*)d_in[11];
    const float* fw = (const float*)d_in[12];
    const float* fbias = (const float*)d_in[13];

    // Workspace (float offsets). Packed f16 features [524288, 14680064) die
    // after K1; p1pad/p2pad/c3t reuse that region (stream-ordered).
    float* ws     = (float*)d_ws;
    float* simbuf = ws;                                    // 524288 f
    _Float16* q16 = (_Float16*)(ws + 524288);              // 9437184 h (packed)
    _Float16* p16 = q16 + 9437184;
    _Float16* n16 = p16 + 9437184;                         // ends f 14680064
    _Float16* p1pad = (_Float16*)(ws + 524288);            // 66*66*32*32 h
    _Float16* p2pad = (_Float16*)(ws + 2754560);           // 34*34*64*32 h
    float* c3t    = ws + 3938304;                          // 4194304 f
    _Float16* w2h = (_Float16*)(ws + 14680064);            // 18432 h
    _Float16* w3h = (_Float16*)(ws + 14689280);            // 73728 h
    float* lossp  = ws + 14726144;                         // 32
    float* outp   = (float*)d_out;

    hipLaunchKernelGGL(k_wprep, dim3(360), dim3(256), 0, stream, w2, w3, w2h, w3h);
    hipLaunchKernelGGL(k_pack, dim3(4608, 3), dim3(256), 0, stream,
                       anchors, positives, negatives, q16, p16, n16);
    hipLaunchKernelGGL(k_f2f_mfma, dim3(2048), dim3(192), 0, stream,
                       q16, p16, n16, amask, pmask, nmask, simbuf);
    hipMemsetAsync(p1pad, 0, (size_t)4460544 * 2, stream);
    hipMemsetAsync(p2pad, 0, (size_t)2367488 * 2, stream);
    hipLaunchKernelGGL(k_conv1pool, dim3(16, 32), dim3(256), 0, stream,
                       simbuf, w1, b1, p1pad);
    hipLaunchKernelGGL(k_conv2_mfma, dim3(4, 32, 32), dim3(256), 0, stream,
                       p1pad, w2h, b2, p2pad);
    hipLaunchKernelGGL(k_conv3_mfma, dim3(4, 32, 32), dim3(256), 0, stream,
                       p2pad, w3h, b3, c3t);
    hipLaunchKernelGGL(k_final, dim3(32), dim3(256), 0, stream,
                       c3t, fw, fbias, amask, pmask, nmask, outp, lossp);
    hipLaunchKernelGGL(k_losssum, dim3(1), dim3(64), 0, stream, lossp, outp);
}